// Round 2
// baseline (483.559 us; speedup 1.0000x reference)
//
#include <hip/hip_runtime.h>

// ---------------------------------------------------------------------------
// MultiHeadAttentionBlock: B=2, S=2048, D=1024, H=16, DK=64, causal mask.
// I/O is FP32 (reference dtype); internal compute bf16 MFMA w/ fp32 accum.
// Pipeline: 3x gemm (Q,K,V proj, fp32->bf16) -> flash attn (bf16) ->
//           gemm (out proj, bf16 x fp32W -> fp32 out)
// ---------------------------------------------------------------------------

typedef __attribute__((ext_vector_type(8))) short bf16x8;     // 8 bf16 = 4 VGPRs
typedef __attribute__((ext_vector_type(4))) float floatx4;    // MFMA C/D

#define S_LEN 2048
#define D_MODEL 1024
#define N_HEADS 16
#define D_HEAD 64
#define M_ROWS 4096   // B*S

__device__ __forceinline__ unsigned short f32_to_bf16(float f) {
  unsigned int u = __builtin_bit_cast(unsigned int, f);
  u += 0x7FFFu + ((u >> 16) & 1u);  // round-to-nearest-even
  return (unsigned short)(u >> 16);
}

// ---------------------------------------------------------------------------
// GEMM: Y[r,n] = sum_d X[r,d]*W[n,d] + bias[n]   (X @ W^T + b)
// X: [4096,1024] (fp32 or bf16), W: [1024,1024] fp32 row-major (n,d).
// 128x128 tile, BK=32, 256 threads = 4 waves, each wave 64x64 (4x4 MFMA).
// fp32 operands are converted to bf16 in registers during LDS staging.
// ---------------------------------------------------------------------------
#define GK 1024
#define GN 1024
#define LDP 40  // 32 + 8 pad elems; row stride 80 B (16B-aligned)

template <bool XF32, bool YF32>
__global__ __launch_bounds__(256, 2) void gemm_bias_bt(
    const void* __restrict__ Xv,
    const float* __restrict__ W,
    const float* __restrict__ bias,
    void* __restrict__ Yv) {
  __shared__ __align__(16) unsigned short As[128 * LDP];
  __shared__ __align__(16) unsigned short Bs[128 * LDP];

  const int r0 = blockIdx.x * 128;
  const int n0 = blockIdx.y * 128;
  const int tid = threadIdx.x;
  const int lane = tid & 63;
  const int wave = tid >> 6;
  const int quad = lane >> 4;
  const int ln = lane & 15;
  const int wm = (wave >> 1) * 64;
  const int wn = (wave & 1) * 64;

  floatx4 acc[4][4];
#pragma unroll
  for (int i = 0; i < 4; i++)
#pragma unroll
    for (int j = 0; j < 4; j++) acc[i][j] = (floatx4){0.f, 0.f, 0.f, 0.f};

  // staging: 128 rows x 32 k / 256 threads = 16 elems each
  const int srow = tid >> 1;
  const int scol = (tid & 1) * 16;
  unsigned short* Asw = As + srow * LDP + scol;
  unsigned short* Bsw = Bs + srow * LDP + scol;
  const float* ApF = (const float*)Xv + (long)(r0 + srow) * GK + scol;
  const unsigned short* ApH = (const unsigned short*)Xv + (long)(r0 + srow) * GK + scol;
  const float* Bp = W + (long)(n0 + srow) * GK + scol;

  for (int k0 = 0; k0 < GK; k0 += 32) {
    unsigned short ua[16] __attribute__((aligned(16)));
    unsigned short ub[16] __attribute__((aligned(16)));
    if constexpr (XF32) {
      float fa[16] __attribute__((aligned(16)));
      *(float4*)(fa + 0)  = *(const float4*)(ApF + k0 + 0);
      *(float4*)(fa + 4)  = *(const float4*)(ApF + k0 + 4);
      *(float4*)(fa + 8)  = *(const float4*)(ApF + k0 + 8);
      *(float4*)(fa + 12) = *(const float4*)(ApF + k0 + 12);
#pragma unroll
      for (int j = 0; j < 16; j++) ua[j] = f32_to_bf16(fa[j]);
    } else {
      *(float4*)(ua + 0) = *(const float4*)(ApH + k0);
      *(float4*)(ua + 8) = *(const float4*)(ApH + k0 + 8);
    }
    {
      float fb[16] __attribute__((aligned(16)));
      *(float4*)(fb + 0)  = *(const float4*)(Bp + k0 + 0);
      *(float4*)(fb + 4)  = *(const float4*)(Bp + k0 + 4);
      *(float4*)(fb + 8)  = *(const float4*)(Bp + k0 + 8);
      *(float4*)(fb + 12) = *(const float4*)(Bp + k0 + 12);
#pragma unroll
      for (int j = 0; j < 16; j++) ub[j] = f32_to_bf16(fb[j]);
    }
    __syncthreads();  // previous tile's LDS reads done
    *(float4*)(Asw) = *(float4*)(ua);
    *(float4*)(Asw + 8) = *(float4*)(ua + 8);
    *(float4*)(Bsw) = *(float4*)(ub);
    *(float4*)(Bsw + 8) = *(float4*)(ub + 8);
    __syncthreads();  // tile staged

    bf16x8 af[4], bfr[4];
#pragma unroll
    for (int mt = 0; mt < 4; mt++)
      af[mt] = *(const bf16x8*)(As + (wm + mt * 16 + ln) * LDP + quad * 8);
#pragma unroll
    for (int nt = 0; nt < 4; nt++)
      bfr[nt] = *(const bf16x8*)(Bs + (wn + nt * 16 + ln) * LDP + quad * 8);
#pragma unroll
    for (int mt = 0; mt < 4; mt++)
#pragma unroll
      for (int nt = 0; nt < 4; nt++)
        acc[mt][nt] = __builtin_amdgcn_mfma_f32_16x16x32_bf16(af[mt], bfr[nt], acc[mt][nt], 0, 0, 0);
  }

  // epilogue: C/D layout row = quad*4+reg, col = ln
#pragma unroll
  for (int nt = 0; nt < 4; nt++) {
    const int n = n0 + wn + nt * 16 + ln;
    const float bv = bias[n];
#pragma unroll
    for (int mt = 0; mt < 4; mt++) {
      const int r = r0 + wm + mt * 16 + quad * 4;
#pragma unroll
      for (int reg = 0; reg < 4; reg++) {
        const float val = acc[mt][nt][reg] + bv;
        if constexpr (YF32)
          ((float*)Yv)[(long)(r + reg) * GN + n] = val;
        else
          ((unsigned short*)Yv)[(long)(r + reg) * GN + n] = f32_to_bf16(val);
      }
    }
  }
}

// ---------------------------------------------------------------------------
// Flash-style causal attention (bf16 in/out, fp32 softmax/accum).
// Q,K,V,O: bf16 [B,S,D]; head h = cols h*64..h*64+63.
// Grid: (S/64, B*H). Block 256 = 4 waves; wave w owns query rows [16w,16w+16).
// ---------------------------------------------------------------------------
#define PADA 72  // 64 + 8 pad elems; row stride 144 B

__global__ __launch_bounds__(256, 2) void attn_causal(
    const unsigned short* __restrict__ Q,
    const unsigned short* __restrict__ K,
    const unsigned short* __restrict__ V,
    unsigned short* __restrict__ O) {
  __shared__ __align__(16) unsigned short Qs[64 * PADA];
  __shared__ __align__(16) unsigned short Ks[64 * PADA];
  __shared__ __align__(16) unsigned short Vs[64 * PADA];  // transposed: [dk][kv]
  __shared__ __align__(16) unsigned short Ps[4][16 * PADA];

  const int qt = blockIdx.x;
  const int bh = blockIdx.y;
  const int b = bh >> 4;
  const int h = bh & 15;
  const int q0 = qt * 64;
  const long base = (long)b * S_LEN * D_MODEL + h * D_HEAD;

  const int tid = threadIdx.x;
  const int lane = tid & 63;
  const int wave = tid >> 6;
  const int quad = lane >> 4;
  const int ln = lane & 15;

  const int srow = tid >> 2;
  const int scol = (tid & 3) * 16;

  {  // load Q tile (visible after first in-loop barrier)
    const unsigned short* qp = Q + base + (long)(q0 + srow) * D_MODEL + scol;
    float4 v0 = *(const float4*)(qp);
    float4 v1 = *(const float4*)(qp + 8);
    *(float4*)(Qs + srow * PADA + scol) = v0;
    *(float4*)(Qs + srow * PADA + scol + 8) = v1;
  }

  float mrow[4], lrow[4];
  floatx4 oacc[4];
#pragma unroll
  for (int r = 0; r < 4; r++) { mrow[r] = -1e30f; lrow[r] = 0.f; }
#pragma unroll
  for (int nt = 0; nt < 4; nt++) oacc[nt] = (floatx4){0.f, 0.f, 0.f, 0.f};

  const float LOG2E = 1.44269504088896340736f;

  for (int kt = 0; kt <= qt; kt++) {
    const int kv0 = kt * 64;
    __syncthreads();  // previous iter's LDS reads done
    {
      const unsigned short* kp = K + base + (long)(kv0 + srow) * D_MODEL + scol;
      float4 v0 = *(const float4*)(kp);
      float4 v1 = *(const float4*)(kp + 8);
      *(float4*)(Ks + srow * PADA + scol) = v0;
      *(float4*)(Ks + srow * PADA + scol + 8) = v1;
      const unsigned short* vp = V + base + (long)(kv0 + srow) * D_MODEL + scol;
      unsigned short tmp[16] __attribute__((aligned(16)));
      *(float4*)(tmp) = *(const float4*)(vp);
      *(float4*)(tmp + 8) = *(const float4*)(vp + 8);
#pragma unroll
      for (int j = 0; j < 16; j++) Vs[(scol + j) * PADA + srow] = tmp[j];
    }
    __syncthreads();  // K/V staged

    // ---- scores: wave computes 16x64 strip
    floatx4 sacc[4];
#pragma unroll
    for (int ct = 0; ct < 4; ct++) sacc[ct] = (floatx4){0.f, 0.f, 0.f, 0.f};
#pragma unroll
    for (int ks = 0; ks < 64; ks += 32) {
      bf16x8 aq = *(const bf16x8*)(Qs + (wave * 16 + ln) * PADA + ks + quad * 8);
#pragma unroll
      for (int ct = 0; ct < 4; ct++) {
        bf16x8 bk = *(const bf16x8*)(Ks + (ct * 16 + ln) * PADA + ks + quad * 8);
        sacc[ct] = __builtin_amdgcn_mfma_f32_16x16x32_bf16(aq, bk, sacc[ct], 0, 0, 0);
      }
    }

    // ---- scale + causal mask + per-row max
    float tmax[4];
#pragma unroll
    for (int reg = 0; reg < 4; reg++) tmax[reg] = -1e30f;
    const int qi = q0 + wave * 16 + quad * 4;  // + reg
#pragma unroll
    for (int ct = 0; ct < 4; ct++) {
      const int kj = kv0 + ct * 16 + ln;
#pragma unroll
      for (int reg = 0; reg < 4; reg++) {
        float s = sacc[ct][reg] * 0.125f;
        if (kj > qi + reg) s = -1e30f;
        sacc[ct][reg] = s;
        tmax[reg] = fmaxf(tmax[reg], s);
      }
    }
#pragma unroll
    for (int off = 1; off < 16; off <<= 1)
#pragma unroll
      for (int reg = 0; reg < 4; reg++)
        tmax[reg] = fmaxf(tmax[reg], __shfl_xor(tmax[reg], off, 64));

    // ---- online softmax update
    float alpha[4], rsum[4];
#pragma unroll
    for (int reg = 0; reg < 4; reg++) {
      const float mnew = fmaxf(mrow[reg], tmax[reg]);
      alpha[reg] = exp2f((mrow[reg] - mnew) * LOG2E);
      mrow[reg] = mnew;
      rsum[reg] = 0.f;
    }
#pragma unroll
    for (int ct = 0; ct < 4; ct++) {
#pragma unroll
      for (int reg = 0; reg < 4; reg++) {
        const float p = exp2f((sacc[ct][reg] - mrow[reg]) * LOG2E);
        rsum[reg] += p;
        Ps[wave][(quad * 4 + reg) * PADA + ct * 16 + ln] = f32_to_bf16(p);
      }
    }
#pragma unroll
    for (int off = 1; off < 16; off <<= 1)
#pragma unroll
      for (int reg = 0; reg < 4; reg++) rsum[reg] += __shfl_xor(rsum[reg], off, 64);
#pragma unroll
    for (int reg = 0; reg < 4; reg++) lrow[reg] = lrow[reg] * alpha[reg] + rsum[reg];
#pragma unroll
    for (int nt = 0; nt < 4; nt++)
#pragma unroll
      for (int reg = 0; reg < 4; reg++) oacc[nt][reg] *= alpha[reg];

    __syncthreads();  // P staged

    // ---- O += P V
#pragma unroll
    for (int ks = 0; ks < 64; ks += 32) {
      bf16x8 ap = *(const bf16x8*)(Ps[wave] + ln * PADA + ks + quad * 8);
#pragma unroll
      for (int nt = 0; nt < 4; nt++) {
        bf16x8 bv = *(const bf16x8*)(Vs + (nt * 16 + ln) * PADA + ks + quad * 8);
        oacc[nt] = __builtin_amdgcn_mfma_f32_16x16x32_bf16(ap, bv, oacc[nt], 0, 0, 0);
      }
    }
  }

  // ---- epilogue
  unsigned short* op = O + base;
#pragma unroll
  for (int nt = 0; nt < 4; nt++) {
#pragma unroll
    for (int reg = 0; reg < 4; reg++) {
      const int r = q0 + wave * 16 + quad * 4 + reg;
      const int c = nt * 16 + ln;
      op[(long)r * D_MODEL + c] = f32_to_bf16(oacc[nt][reg] / lrow[reg]);
    }
  }
}

// ---------------------------------------------------------------------------
extern "C" void kernel_launch(void* const* d_in, const int* in_sizes, int n_in,
                              void* d_out, int out_size, void* d_ws, size_t ws_size,
                              hipStream_t stream) {
  const float* q = (const float*)d_in[0];
  const float* k = (const float*)d_in[1];
  const float* v = (const float*)d_in[2];
  // d_in[3] = causal mask (known tril; hardcoded in attn kernel)
  const float* w_q = (const float*)d_in[4];
  const float* b_q = (const float*)d_in[5];
  const float* w_k = (const float*)d_in[6];
  const float* b_k = (const float*)d_in[7];
  const float* w_v = (const float*)d_in[8];
  const float* b_v = (const float*)d_in[9];
  const float* w_o = (const float*)d_in[10];
  const float* b_o = (const float*)d_in[11];
  float* out = (float*)d_out;

  unsigned short* ws = (unsigned short*)d_ws;
  const long NE = (long)M_ROWS * D_MODEL;  // 4M elems = 8 MiB bf16 each
  unsigned short* Qp = ws;
  unsigned short* Kp = ws + NE;
  unsigned short* Vp = ws + 2 * NE;
  unsigned short* AO = ws + 3 * NE;

  dim3 gemm_grid(M_ROWS / 128, GN / 128);  // (32, 8)
  gemm_bias_bt<true, false><<<gemm_grid, 256, 0, stream>>>(q, w_q, b_q, Qp);
  gemm_bias_bt<true, false><<<gemm_grid, 256, 0, stream>>>(k, w_k, b_k, Kp);
  gemm_bias_bt<true, false><<<gemm_grid, 256, 0, stream>>>(v, w_v, b_v, Vp);
  attn_causal<<<dim3(S_LEN / 64, 2 * N_HEADS), 256, 0, stream>>>(Qp, Kp, Vp, AO);
  gemm_bias_bt<false, true><<<gemm_grid, 256, 0, stream>>>(AO, w_o, b_o, out);
}

// Round 3
// 384.745 us; speedup vs baseline: 1.2568x; 1.2568x over previous
//
#include <hip/hip_runtime.h>

// ---------------------------------------------------------------------------
// MultiHeadAttentionBlock: B=2, S=2048, D=1024, H=16, DK=64, causal.
// FP32 I/O; bf16 MFMA compute with fp32 accumulate.
// r2: fused QKV projection (grid.z=3), V written transposed, barrier-free
//     per-wave flash attention (S^T/O^T scheme), 64x128 out-proj tiles.
// ---------------------------------------------------------------------------

typedef __attribute__((ext_vector_type(8))) short bf16x8;     // 8 bf16 = 4 VGPRs
typedef __attribute__((ext_vector_type(4))) float floatx4;    // MFMA C/D
typedef __attribute__((ext_vector_type(4))) unsigned short u16x4;  // 8B packed bf16

#define S_LEN 2048
#define D_MODEL 1024
#define N_HEADS 16
#define D_HEAD 64
#define M_ROWS 4096   // B*S

__device__ __forceinline__ unsigned short f32_to_bf16(float f) {
  unsigned int u = __builtin_bit_cast(unsigned int, f);
  u += 0x7FFFu + ((u >> 16) & 1u);  // RNE
  return (unsigned short)(u >> 16);
}

// ---------------------------------------------------------------------------
// Fused QKV projection: z = blockIdx.z selects (X, W, bias, Y).
// Y[r,n] = sum_d X[r,d]*W[n,d] + bias[n].  X fp32 [4096,1024], W fp32 [n,d].
// z=0,1: Y bf16 [r][n].  z=2: Y^T bf16 [n][4096+r] (V pre-transposed for attn).
// 128x128 tile, BK=32, 4 waves x (64x64).
// ---------------------------------------------------------------------------
#define GK 1024
#define GN 1024
#define LDP 40  // 32 + 8 pad; row stride 80 B

__global__ __launch_bounds__(256, 2) void qkv_gemm(
    const float* __restrict__ Xq, const float* __restrict__ Xk, const float* __restrict__ Xv,
    const float* __restrict__ Wq, const float* __restrict__ Wk, const float* __restrict__ Wv,
    const float* __restrict__ bq, const float* __restrict__ bk, const float* __restrict__ bv,
    unsigned short* __restrict__ Yq, unsigned short* __restrict__ Yk, unsigned short* __restrict__ Yvt) {
  __shared__ __align__(16) unsigned short As[128 * LDP];
  __shared__ __align__(16) unsigned short Bs[128 * LDP];

  const int z = blockIdx.z;
  const float* X = (z == 0) ? Xq : ((z == 1) ? Xk : Xv);
  const float* W = (z == 0) ? Wq : ((z == 1) ? Wk : Wv);
  const float* bias = (z == 0) ? bq : ((z == 1) ? bk : bv);

  const int r0 = blockIdx.x * 128;
  const int n0 = blockIdx.y * 128;
  const int tid = threadIdx.x;
  const int lane = tid & 63;
  const int wave = tid >> 6;
  const int quad = lane >> 4;
  const int ln = lane & 15;
  const int wm = (wave >> 1) * 64;
  const int wn = (wave & 1) * 64;

  floatx4 acc[4][4];
#pragma unroll
  for (int i = 0; i < 4; i++)
#pragma unroll
    for (int j = 0; j < 4; j++) acc[i][j] = (floatx4){0.f, 0.f, 0.f, 0.f};

  const int srow = tid >> 1;
  const int scol = (tid & 1) * 16;
  unsigned short* Asw = As + srow * LDP + scol;
  unsigned short* Bsw = Bs + srow * LDP + scol;
  const float* Ap = X + (long)(r0 + srow) * GK + scol;
  const float* Bp = W + (long)(n0 + srow) * GK + scol;

  for (int k0 = 0; k0 < GK; k0 += 32) {
    unsigned short ua[16] __attribute__((aligned(16)));
    unsigned short ub[16] __attribute__((aligned(16)));
    {
      float fa[16] __attribute__((aligned(16)));
      *(float4*)(fa + 0)  = *(const float4*)(Ap + k0 + 0);
      *(float4*)(fa + 4)  = *(const float4*)(Ap + k0 + 4);
      *(float4*)(fa + 8)  = *(const float4*)(Ap + k0 + 8);
      *(float4*)(fa + 12) = *(const float4*)(Ap + k0 + 12);
      float fb[16] __attribute__((aligned(16)));
      *(float4*)(fb + 0)  = *(const float4*)(Bp + k0 + 0);
      *(float4*)(fb + 4)  = *(const float4*)(Bp + k0 + 4);
      *(float4*)(fb + 8)  = *(const float4*)(Bp + k0 + 8);
      *(float4*)(fb + 12) = *(const float4*)(Bp + k0 + 12);
#pragma unroll
      for (int j = 0; j < 16; j++) { ua[j] = f32_to_bf16(fa[j]); ub[j] = f32_to_bf16(fb[j]); }
    }
    __syncthreads();
    *(float4*)(Asw) = *(float4*)(ua);
    *(float4*)(Asw + 8) = *(float4*)(ua + 8);
    *(float4*)(Bsw) = *(float4*)(ub);
    *(float4*)(Bsw + 8) = *(float4*)(ub + 8);
    __syncthreads();

    bf16x8 af[4], bfr[4];
#pragma unroll
    for (int mt = 0; mt < 4; mt++)
      af[mt] = *(const bf16x8*)(As + (wm + mt * 16 + ln) * LDP + quad * 8);
#pragma unroll
    for (int nt = 0; nt < 4; nt++)
      bfr[nt] = *(const bf16x8*)(Bs + (wn + nt * 16 + ln) * LDP + quad * 8);
#pragma unroll
    for (int mt = 0; mt < 4; mt++)
#pragma unroll
      for (int nt = 0; nt < 4; nt++)
        acc[mt][nt] = __builtin_amdgcn_mfma_f32_16x16x32_bf16(af[mt], bfr[nt], acc[mt][nt], 0, 0, 0);
  }

  // epilogue: C/D row = quad*4+reg, col = ln
#pragma unroll
  for (int nt = 0; nt < 4; nt++) {
    const int n = n0 + wn + nt * 16 + ln;
    const float bv = bias[n];
#pragma unroll
    for (int mt = 0; mt < 4; mt++) {
      const int r = r0 + wm + mt * 16 + quad * 4;
      if (z == 2) {  // V^T: Yvt[n][r..r+3], regs are r-consecutive
        u16x4 pk;
#pragma unroll
        for (int reg = 0; reg < 4; reg++) pk[reg] = f32_to_bf16(acc[mt][nt][reg] + bv);
        *(u16x4*)(Yvt + (long)n * M_ROWS + r) = pk;
      } else {
        unsigned short* Y = (z == 0) ? Yq : Yk;
#pragma unroll
        for (int reg = 0; reg < 4; reg++)
          Y[(long)(r + reg) * GN + n] = f32_to_bf16(acc[mt][nt][reg] + bv);
      }
    }
  }
}

// ---------------------------------------------------------------------------
// Out projection: Y fp32 = AO(bf16) @ W^T + b.  64x128 tile -> 512 blocks.
// ---------------------------------------------------------------------------
__global__ __launch_bounds__(256, 2) void out_gemm(
    const unsigned short* __restrict__ X,   // bf16 [4096,1024]
    const float* __restrict__ W,            // fp32 [1024,1024]
    const float* __restrict__ bias,
    float* __restrict__ Y) {
  __shared__ __align__(16) unsigned short As[64 * LDP];
  __shared__ __align__(16) unsigned short Bs[128 * LDP];

  const int r0 = blockIdx.x * 64;
  const int n0 = blockIdx.y * 128;
  const int tid = threadIdx.x;
  const int lane = tid & 63;
  const int wave = tid >> 6;
  const int quad = lane >> 4;
  const int ln = lane & 15;
  const int wm = (wave >> 1) * 32;  // 2x2 wave layout: 32 rows x 64 cols each
  const int wn = (wave & 1) * 64;

  floatx4 acc[2][4];
#pragma unroll
  for (int i = 0; i < 2; i++)
#pragma unroll
    for (int j = 0; j < 4; j++) acc[i][j] = (floatx4){0.f, 0.f, 0.f, 0.f};

  // A staging: 64x32 bf16 / 256 thr = 8 elems (one 16B load)
  const int arow = tid >> 2;
  const int acol = (tid & 3) * 8;
  const unsigned short* Ap = X + (long)(r0 + arow) * GK + acol;
  unsigned short* Asw = As + arow * LDP + acol;
  // B staging: 128x32 fp32 / 256 thr = 16 elems
  const int brow = tid >> 1;
  const int bcol = (tid & 1) * 16;
  const float* Bp = W + (long)(n0 + brow) * GK + bcol;
  unsigned short* Bsw = Bs + brow * LDP + bcol;

  for (int k0 = 0; k0 < GK; k0 += 32) {
    float4 a0 = *(const float4*)(Ap + k0);
    unsigned short ub[16] __attribute__((aligned(16)));
    {
      float fb[16] __attribute__((aligned(16)));
      *(float4*)(fb + 0)  = *(const float4*)(Bp + k0 + 0);
      *(float4*)(fb + 4)  = *(const float4*)(Bp + k0 + 4);
      *(float4*)(fb + 8)  = *(const float4*)(Bp + k0 + 8);
      *(float4*)(fb + 12) = *(const float4*)(Bp + k0 + 12);
#pragma unroll
      for (int j = 0; j < 16; j++) ub[j] = f32_to_bf16(fb[j]);
    }
    __syncthreads();
    *(float4*)(Asw) = a0;
    *(float4*)(Bsw) = *(float4*)(ub);
    *(float4*)(Bsw + 8) = *(float4*)(ub + 8);
    __syncthreads();

    bf16x8 af[2], bfr[4];
#pragma unroll
    for (int mt = 0; mt < 2; mt++)
      af[mt] = *(const bf16x8*)(As + (wm + mt * 16 + ln) * LDP + quad * 8);
#pragma unroll
    for (int nt = 0; nt < 4; nt++)
      bfr[nt] = *(const bf16x8*)(Bs + (wn + nt * 16 + ln) * LDP + quad * 8);
#pragma unroll
    for (int mt = 0; mt < 2; mt++)
#pragma unroll
      for (int nt = 0; nt < 4; nt++)
        acc[mt][nt] = __builtin_amdgcn_mfma_f32_16x16x32_bf16(af[mt], bfr[nt], acc[mt][nt], 0, 0, 0);
  }

#pragma unroll
  for (int nt = 0; nt < 4; nt++) {
    const int n = n0 + wn + nt * 16 + ln;
    const float bv = bias[n];
#pragma unroll
    for (int mt = 0; mt < 2; mt++) {
      const int r = r0 + wm + mt * 16 + quad * 4;
#pragma unroll
      for (int reg = 0; reg < 4; reg++)
        Y[(long)(r + reg) * GN + n] = acc[mt][nt][reg] + bv;
    }
  }
}

// ---------------------------------------------------------------------------
// Barrier-free per-wave flash attention (causal).
// One 64-thread block = one wave = one 16-row q-strip of one (b,h).
// S^T = K Q^T  (C-layout: row=kv, col=q=ln)  -> softmax cols on ln lanes
// O^T = V^T P^T (V^T direct from global Vt[n][r]; P^T via per-wave LDS).
// Zero __syncthreads. K/V fragments loaded straight from global (L2-served;
// grid.x = bh keeps a head's K/V on one XCD's L2).
// ---------------------------------------------------------------------------
#define PSTR 72  // P-buffer row stride (elems); 16 rows

__global__ __launch_bounds__(64, 3) void attn_causal(
    const unsigned short* __restrict__ Q,   // bf16 [B,S,D]
    const unsigned short* __restrict__ K,   // bf16 [B,S,D]
    const unsigned short* __restrict__ Vt,  // bf16 [D][4096]  (n = h*64+dk, r = b*2048+s)
    unsigned short* __restrict__ O) {       // bf16 [B,S,D]
  __shared__ __align__(16) unsigned short Pb[16 * PSTR];

  const int bh = blockIdx.x;   // 0..31  (x-major -> same head pins to one XCD)
  const int s = blockIdx.y;    // strip 0..127
  const int b = bh >> 4;
  const int h = bh & 15;
  const int q0 = s * 16;

  const int lane = threadIdx.x;
  const int quad = lane >> 4;
  const int ln = lane & 15;

  const unsigned short* Qb = Q + (long)b * S_LEN * D_MODEL + h * D_HEAD;
  const unsigned short* Kb = K + (long)b * S_LEN * D_MODEL + h * D_HEAD;
  const unsigned short* Vb = Vt + (long)h * D_HEAD * M_ROWS + b * S_LEN;  // + dk*4096 + s

  // Q B-frags (persist across the whole kv loop): B[k=d][n=q]: lane needs
  // Q[q0+ln][ks+quad*8 .. +7]
  bf16x8 qf[2];
  qf[0] = *(const bf16x8*)(Qb + (long)(q0 + ln) * D_MODEL + quad * 8);
  qf[1] = *(const bf16x8*)(Qb + (long)(q0 + ln) * D_MODEL + 32 + quad * 8);

  float m = -1e30f, l = 0.f;
  floatx4 oacc[4];
#pragma unroll
  for (int nt = 0; nt < 4; nt++) oacc[nt] = (floatx4){0.f, 0.f, 0.f, 0.f};

  const float LOG2E = 1.44269504088896340736f;
  const int nkt = (s >> 2) + 1;

  for (int kt = 0; kt < nkt; kt++) {
    const int kv0 = kt * 64;

    // ---- direct global fragment loads (16 B / lane each)
    bf16x8 kf[4][2], vf[4][2];
#pragma unroll
    for (int ct = 0; ct < 4; ct++) {
      const unsigned short* kp = Kb + (long)(kv0 + ct * 16 + ln) * D_MODEL + quad * 8;
      kf[ct][0] = *(const bf16x8*)(kp);
      kf[ct][1] = *(const bf16x8*)(kp + 32);
    }
#pragma unroll
    for (int nt = 0; nt < 4; nt++) {
      const unsigned short* vp = Vb + (long)(nt * 16 + ln) * M_ROWS + kv0 + quad * 8;
      vf[nt][0] = *(const bf16x8*)(vp);
      vf[nt][1] = *(const bf16x8*)(vp + 32);
    }

    // ---- S^T = K Q^T : sacc[ct] row=kv_local(ct*16+quad*4+reg), col=q(ln)
    floatx4 sacc[4];
#pragma unroll
    for (int ct = 0; ct < 4; ct++) {
      sacc[ct] = (floatx4){0.f, 0.f, 0.f, 0.f};
      sacc[ct] = __builtin_amdgcn_mfma_f32_16x16x32_bf16(kf[ct][0], qf[0], sacc[ct], 0, 0, 0);
      sacc[ct] = __builtin_amdgcn_mfma_f32_16x16x32_bf16(kf[ct][1], qf[1], sacc[ct], 0, 0, 0);
    }

    // ---- scale (+ causal mask, last tile only) + per-lane max
    float tmax = -1e30f;
    if (kt == nkt - 1) {
      const int qg = q0 + ln;
#pragma unroll
      for (int ct = 0; ct < 4; ct++) {
        const int kvb = kv0 + ct * 16 + quad * 4;
#pragma unroll
        for (int reg = 0; reg < 4; reg++) {
          float sv = sacc[ct][reg] * 0.125f;
          if (kvb + reg > qg) sv = -1e30f;
          sacc[ct][reg] = sv;
          tmax = fmaxf(tmax, sv);
        }
      }
    } else {
#pragma unroll
      for (int ct = 0; ct < 4; ct++)
#pragma unroll
        for (int reg = 0; reg < 4; reg++) {
          const float sv = sacc[ct][reg] * 0.125f;
          sacc[ct][reg] = sv;
          tmax = fmaxf(tmax, sv);
        }
    }
    // column (q) reduce: values for q=ln live on lanes {ln,16+ln,32+ln,48+ln}
    tmax = fmaxf(tmax, __shfl_xor(tmax, 16, 64));
    tmax = fmaxf(tmax, __shfl_xor(tmax, 32, 64));

    // ---- online softmax
    const float mnew = fmaxf(m, tmax);
    const float alpha = exp2f((m - mnew) * LOG2E);
    m = mnew;
    float rsum = 0.f;
#pragma unroll
    for (int ct = 0; ct < 4; ct++) {
      u16x4 pk;
#pragma unroll
      for (int reg = 0; reg < 4; reg++) {
        const float p = exp2f((sacc[ct][reg] - m) * LOG2E);
        rsum += p;
        pk[reg] = f32_to_bf16(p);
      }
      // P[q=ln][kv=ct*16+quad*4 .. +3]  (8 B write)
      *(u16x4*)(Pb + ln * PSTR + ct * 16 + quad * 4) = pk;
    }
    rsum += __shfl_xor(rsum, 16, 64);
    rsum += __shfl_xor(rsum, 32, 64);
    l = l * alpha + rsum;
#pragma unroll
    for (int nt = 0; nt < 4; nt++)
#pragma unroll
      for (int reg = 0; reg < 4; reg++) oacc[nt][reg] *= alpha;

    __builtin_amdgcn_wave_barrier();  // keep ds_reads below the ds_writes

    // ---- P^T B-frags: B[k=kv][n=q]: lane reads P[ln][ks+quad*8 .. +7]
    bf16x8 pf0 = *(const bf16x8*)(Pb + ln * PSTR + quad * 8);
    bf16x8 pf1 = *(const bf16x8*)(Pb + ln * PSTR + 32 + quad * 8);

    // ---- O^T += V^T P^T
#pragma unroll
    for (int nt = 0; nt < 4; nt++) {
      oacc[nt] = __builtin_amdgcn_mfma_f32_16x16x32_bf16(vf[nt][0], pf0, oacc[nt], 0, 0, 0);
      oacc[nt] = __builtin_amdgcn_mfma_f32_16x16x32_bf16(vf[nt][1], pf1, oacc[nt], 0, 0, 0);
    }
    __builtin_amdgcn_wave_barrier();  // don't hoist next iter's P writes above reads
  }

  // ---- epilogue: O^T C-layout -> O[q][dk]; regs are dk-consecutive -> 8B stores
  const float inv = 1.0f / l;
  unsigned short* op = O + (long)b * S_LEN * D_MODEL + (long)(q0 + ln) * D_MODEL + h * D_HEAD;
#pragma unroll
  for (int nt = 0; nt < 4; nt++) {
    u16x4 pk;
#pragma unroll
    for (int reg = 0; reg < 4; reg++) pk[reg] = f32_to_bf16(oacc[nt][reg] * inv);
    *(u16x4*)(op + nt * 16 + quad * 4) = pk;
  }
}

// ---------------------------------------------------------------------------
extern "C" void kernel_launch(void* const* d_in, const int* in_sizes, int n_in,
                              void* d_out, int out_size, void* d_ws, size_t ws_size,
                              hipStream_t stream) {
  const float* q = (const float*)d_in[0];
  const float* k = (const float*)d_in[1];
  const float* v = (const float*)d_in[2];
  // d_in[3] = causal mask (hardcoded)
  const float* w_q = (const float*)d_in[4];
  const float* b_q = (const float*)d_in[5];
  const float* w_k = (const float*)d_in[6];
  const float* b_k = (const float*)d_in[7];
  const float* w_v = (const float*)d_in[8];
  const float* b_v = (const float*)d_in[9];
  const float* w_o = (const float*)d_in[10];
  const float* b_o = (const float*)d_in[11];
  float* out = (float*)d_out;

  unsigned short* ws = (unsigned short*)d_ws;
  const long NE = (long)M_ROWS * D_MODEL;  // 4M elems = 8 MiB bf16 each
  unsigned short* Qp = ws;
  unsigned short* Kp = ws + NE;
  unsigned short* Vpt = ws + 2 * NE;   // transposed [D][4096]
  unsigned short* AO = ws + 3 * NE;

  qkv_gemm<<<dim3(M_ROWS / 128, GN / 128, 3), 256, 0, stream>>>(
      q, k, v, w_q, w_k, w_v, b_q, b_k, b_v, Qp, Kp, Vpt);
  attn_causal<<<dim3(2 * N_HEADS, S_LEN / 16), 64, 0, stream>>>(Qp, Kp, Vpt, AO);
  out_gemm<<<dim3(M_ROWS / 64, GN / 128), 256, 0, stream>>>(AO, w_o, b_o, out);
}

// Round 4
// 319.817 us; speedup vs baseline: 1.5120x; 1.2030x over previous
//
#include <hip/hip_runtime.h>

// ---------------------------------------------------------------------------
// MultiHeadAttentionBlock: B=2, S=2048, D=1024, H=16, DK=64, causal.
// FP32 I/O; bf16 MFMA compute, fp32 accumulate.
// r4: weights pre-converted to bf16 (cvt_w); Q projection pre-scaled by
//     0.125*log2e (softmax runs in exp2 domain); attention blocks process
//     balanced strip-pairs (s, 127-s) -> uniform work, 16 waves/CU.
// ---------------------------------------------------------------------------

typedef __attribute__((ext_vector_type(8))) short bf16x8;     // 8 bf16 = 4 VGPRs
typedef __attribute__((ext_vector_type(4))) float floatx4;    // MFMA C/D
typedef __attribute__((ext_vector_type(4))) unsigned short u16x4;  // 8B packed bf16

#define S_LEN 2048
#define D_MODEL 1024
#define N_HEADS 16
#define D_HEAD 64
#define M_ROWS 4096   // B*S
#define QSCALE 0.18033688011112042f  // 0.125 * log2(e)

__device__ __forceinline__ unsigned short f32_to_bf16(float f) {
  unsigned int u = __builtin_bit_cast(unsigned int, f);
  u += 0x7FFFu + ((u >> 16) & 1u);  // RNE
  return (unsigned short)(u >> 16);
}

// ---------------------------------------------------------------------------
// Weight fp32 -> bf16 pre-pass: 4 x [1024,1024]. grid (256,4) x 256 thr.
// ---------------------------------------------------------------------------
__global__ __launch_bounds__(256) void cvt_w(
    const float* __restrict__ w0, const float* __restrict__ w1,
    const float* __restrict__ w2, const float* __restrict__ w3,
    unsigned short* __restrict__ dst) {
  const int z = blockIdx.y;
  const float* src = (z == 0) ? w0 : (z == 1) ? w1 : (z == 2) ? w2 : w3;
  unsigned short* d = dst + ((long)z << 20);
  const int n4 = 1 << 18;  // 2^20 elems / 4
  for (int i = blockIdx.x * 256 + threadIdx.x; i < n4; i += gridDim.x * 256) {
    float4 f = ((const float4*)src)[i];
    u16x4 o;
    o[0] = f32_to_bf16(f.x); o[1] = f32_to_bf16(f.y);
    o[2] = f32_to_bf16(f.z); o[3] = f32_to_bf16(f.w);
    ((u16x4*)d)[i] = o;
  }
}

// ---------------------------------------------------------------------------
// Fused QKV projection. z = blockIdx.z.  Y = X @ W^T + b.
// X fp32 [4096,1024] (cvt to bf16 in staging), W bf16 [1024,1024] (n,d).
// z=0: Y = (X Wq^T + bq) * QSCALE  (bf16 [r][n])
// z=1: Y bf16 [r][n].   z=2: Y^T bf16 [n][4096] (V pre-transposed).
// 128x128 tile, BK=32, 4 waves x (64x64).
// ---------------------------------------------------------------------------
#define GK 1024
#define GN 1024
#define LDP 40  // 32 + 8 pad; row stride 80 B

__global__ __launch_bounds__(256, 3) void qkv_gemm(
    const float* __restrict__ Xq, const float* __restrict__ Xk, const float* __restrict__ Xv,
    const unsigned short* __restrict__ Wb,  // bf16, 4 x 1M: [wq|wk|wv|wo]
    const float* __restrict__ bq, const float* __restrict__ bk, const float* __restrict__ bv,
    unsigned short* __restrict__ Yq, unsigned short* __restrict__ Yk,
    unsigned short* __restrict__ Yvt) {
  __shared__ __align__(16) unsigned short As[128 * LDP];
  __shared__ __align__(16) unsigned short Bs[128 * LDP];

  const int z = blockIdx.z;
  const float* X = (z == 0) ? Xq : ((z == 1) ? Xk : Xv);
  const unsigned short* W = Wb + ((long)z << 20);
  const float* bias = (z == 0) ? bq : ((z == 1) ? bk : bv);

  const int r0 = blockIdx.x * 128;
  const int n0 = blockIdx.y * 128;
  const int tid = threadIdx.x;
  const int lane = tid & 63;
  const int wave = tid >> 6;
  const int quad = lane >> 4;
  const int ln = lane & 15;
  const int wm = (wave >> 1) * 64;
  const int wn = (wave & 1) * 64;

  floatx4 acc[4][4];
#pragma unroll
  for (int i = 0; i < 4; i++)
#pragma unroll
    for (int j = 0; j < 4; j++) acc[i][j] = (floatx4){0.f, 0.f, 0.f, 0.f};

  const int srow = tid >> 1;
  const int scol = (tid & 1) * 16;
  unsigned short* Asw = As + srow * LDP + scol;
  unsigned short* Bsw = Bs + srow * LDP + scol;
  const float* Ap = X + (long)(r0 + srow) * GK + scol;
  const unsigned short* Bp = W + (long)(n0 + srow) * GK + scol;

  for (int k0 = 0; k0 < GK; k0 += 32) {
    unsigned short ua[16] __attribute__((aligned(16)));
    float4 b0 = *(const float4*)(Bp + k0);      // 8 bf16
    float4 b1 = *(const float4*)(Bp + k0 + 8);
    {
      float fa[16] __attribute__((aligned(16)));
      *(float4*)(fa + 0)  = *(const float4*)(Ap + k0 + 0);
      *(float4*)(fa + 4)  = *(const float4*)(Ap + k0 + 4);
      *(float4*)(fa + 8)  = *(const float4*)(Ap + k0 + 8);
      *(float4*)(fa + 12) = *(const float4*)(Ap + k0 + 12);
#pragma unroll
      for (int j = 0; j < 16; j++) ua[j] = f32_to_bf16(fa[j]);
    }
    __syncthreads();
    *(float4*)(Asw) = *(float4*)(ua);
    *(float4*)(Asw + 8) = *(float4*)(ua + 8);
    *(float4*)(Bsw) = b0;
    *(float4*)(Bsw + 8) = b1;
    __syncthreads();

    bf16x8 af[4], bfr[4];
#pragma unroll
    for (int mt = 0; mt < 4; mt++)
      af[mt] = *(const bf16x8*)(As + (wm + mt * 16 + ln) * LDP + quad * 8);
#pragma unroll
    for (int nt = 0; nt < 4; nt++)
      bfr[nt] = *(const bf16x8*)(Bs + (wn + nt * 16 + ln) * LDP + quad * 8);
#pragma unroll
    for (int mt = 0; mt < 4; mt++)
#pragma unroll
      for (int nt = 0; nt < 4; nt++)
        acc[mt][nt] = __builtin_amdgcn_mfma_f32_16x16x32_bf16(af[mt], bfr[nt], acc[mt][nt], 0, 0, 0);
  }

  // epilogue: C/D row = quad*4+reg, col = ln
#pragma unroll
  for (int nt = 0; nt < 4; nt++) {
    const int n = n0 + wn + nt * 16 + ln;
    const float bv = bias[n];
#pragma unroll
    for (int mt = 0; mt < 4; mt++) {
      const int r = r0 + wm + mt * 16 + quad * 4;
      if (z == 2) {  // V^T: Yvt[n][r..r+3]
        u16x4 pk;
#pragma unroll
        for (int reg = 0; reg < 4; reg++) pk[reg] = f32_to_bf16(acc[mt][nt][reg] + bv);
        *(u16x4*)(Yvt + (long)n * M_ROWS + r) = pk;
      } else if (z == 0) {  // Q pre-scaled for exp2-domain softmax
#pragma unroll
        for (int reg = 0; reg < 4; reg++)
          Yq[(long)(r + reg) * GN + n] = f32_to_bf16((acc[mt][nt][reg] + bv) * QSCALE);
      } else {
#pragma unroll
        for (int reg = 0; reg < 4; reg++)
          Yk[(long)(r + reg) * GN + n] = f32_to_bf16(acc[mt][nt][reg] + bv);
      }
    }
  }
}

// ---------------------------------------------------------------------------
// Out projection: Y fp32 = AO(bf16) @ Wo(bf16)^T + b.  64x128 tile, 512 blocks.
// ---------------------------------------------------------------------------
__global__ __launch_bounds__(256, 3) void out_gemm(
    const unsigned short* __restrict__ X,   // bf16 [4096,1024]
    const unsigned short* __restrict__ W,   // bf16 [1024,1024]
    const float* __restrict__ bias,
    float* __restrict__ Y) {
  __shared__ __align__(16) unsigned short As[64 * LDP];
  __shared__ __align__(16) unsigned short Bs[128 * LDP];

  const int r0 = blockIdx.x * 64;
  const int n0 = blockIdx.y * 128;
  const int tid = threadIdx.x;
  const int lane = tid & 63;
  const int wave = tid >> 6;
  const int quad = lane >> 4;
  const int ln = lane & 15;
  const int wm = (wave >> 1) * 32;
  const int wn = (wave & 1) * 64;

  floatx4 acc[2][4];
#pragma unroll
  for (int i = 0; i < 2; i++)
#pragma unroll
    for (int j = 0; j < 4; j++) acc[i][j] = (floatx4){0.f, 0.f, 0.f, 0.f};

  const int arow = tid >> 2;
  const int acol = (tid & 3) * 8;
  const unsigned short* Ap = X + (long)(r0 + arow) * GK + acol;
  unsigned short* Asw = As + arow * LDP + acol;
  const int brow = tid >> 1;
  const int bcol = (tid & 1) * 16;
  const unsigned short* Bp = W + (long)(n0 + brow) * GK + bcol;
  unsigned short* Bsw = Bs + brow * LDP + bcol;

  for (int k0 = 0; k0 < GK; k0 += 32) {
    float4 a0 = *(const float4*)(Ap + k0);
    float4 b0 = *(const float4*)(Bp + k0);
    float4 b1 = *(const float4*)(Bp + k0 + 8);
    __syncthreads();
    *(float4*)(Asw) = a0;
    *(float4*)(Bsw) = b0;
    *(float4*)(Bsw + 8) = b1;
    __syncthreads();

    bf16x8 af[2], bfr[4];
#pragma unroll
    for (int mt = 0; mt < 2; mt++)
      af[mt] = *(const bf16x8*)(As + (wm + mt * 16 + ln) * LDP + quad * 8);
#pragma unroll
    for (int nt = 0; nt < 4; nt++)
      bfr[nt] = *(const bf16x8*)(Bs + (wn + nt * 16 + ln) * LDP + quad * 8);
#pragma unroll
    for (int mt = 0; mt < 2; mt++)
#pragma unroll
      for (int nt = 0; nt < 4; nt++)
        acc[mt][nt] = __builtin_amdgcn_mfma_f32_16x16x32_bf16(af[mt], bfr[nt], acc[mt][nt], 0, 0, 0);
  }

#pragma unroll
  for (int nt = 0; nt < 4; nt++) {
    const int n = n0 + wn + nt * 16 + ln;
    const float bv = bias[n];
#pragma unroll
    for (int mt = 0; mt < 2; mt++) {
      const int r = r0 + wm + mt * 16 + quad * 4;
#pragma unroll
      for (int reg = 0; reg < 4; reg++)
        Y[(long)(r + reg) * GN + n] = acc[mt][nt][reg] + bv;
    }
  }
}

// ---------------------------------------------------------------------------
// Balanced per-wave flash attention (causal), exp2-domain (Q pre-scaled).
// One 64-thread block = one wave, processes strips s=pr and s=127-pr
// sequentially -> every block does exactly (pr/4+1)+((127-pr)/4+1) ~ 33 iters.
// S^T = K Q^T (C-layout row=kv, col=q); O^T = V^T P^T (P^T via per-wave LDS).
// No __syncthreads anywhere.
// ---------------------------------------------------------------------------
#define PSTR 72

__global__ __launch_bounds__(64, 4) void attn_causal(
    const unsigned short* __restrict__ Q,   // bf16 [B,S,D], pre-scaled
    const unsigned short* __restrict__ K,   // bf16 [B,S,D]
    const unsigned short* __restrict__ Vt,  // bf16 [D][4096]
    unsigned short* __restrict__ O) {       // bf16 [B,S,D]
  __shared__ __align__(16) unsigned short Pb[16 * PSTR];

  const int bh = blockIdx.x;   // 0..31
  const int pr = blockIdx.y;   // 0..63
  const int b = bh >> 4;
  const int h = bh & 15;

  const int lane = threadIdx.x;
  const int quad = lane >> 4;
  const int ln = lane & 15;

  const unsigned short* Qb = Q + (long)b * S_LEN * D_MODEL + h * D_HEAD;
  const unsigned short* Kb = K + (long)b * S_LEN * D_MODEL + h * D_HEAD;
  const unsigned short* Vb = Vt + (long)h * D_HEAD * M_ROWS + b * S_LEN;

#pragma unroll 1
  for (int half = 0; half < 2; half++) {
    const int s = half ? (127 - pr) : pr;
    const int q0 = s * 16;
    const int nkt = (s >> 2) + 1;

    // Q B-frags persist across the kv loop: B[k=d][n=q=ln]
    bf16x8 qf[2];
    qf[0] = *(const bf16x8*)(Qb + (long)(q0 + ln) * D_MODEL + quad * 8);
    qf[1] = *(const bf16x8*)(Qb + (long)(q0 + ln) * D_MODEL + 32 + quad * 8);

    float m = -1e30f, l = 0.f;
    floatx4 oacc[4];
#pragma unroll
    for (int nt = 0; nt < 4; nt++) oacc[nt] = (floatx4){0.f, 0.f, 0.f, 0.f};

    for (int kt = 0; kt < nkt; kt++) {
      const int kv0 = kt * 64;

      bf16x8 kf[4][2], vf[4][2];
#pragma unroll
      for (int ct = 0; ct < 4; ct++) {
        const unsigned short* kp = Kb + (long)(kv0 + ct * 16 + ln) * D_MODEL + quad * 8;
        kf[ct][0] = *(const bf16x8*)(kp);
        kf[ct][1] = *(const bf16x8*)(kp + 32);
      }
#pragma unroll
      for (int nt = 0; nt < 4; nt++) {
        const unsigned short* vp = Vb + (long)(nt * 16 + ln) * M_ROWS + kv0 + quad * 8;
        vf[nt][0] = *(const bf16x8*)(vp);
        vf[nt][1] = *(const bf16x8*)(vp + 32);
      }

      // S^T = K Q^T : sacc[ct] row=kv(ct*16+quad*4+reg), col=q(ln)
      floatx4 sacc[4];
#pragma unroll
      for (int ct = 0; ct < 4; ct++) {
        sacc[ct] = (floatx4){0.f, 0.f, 0.f, 0.f};
        sacc[ct] = __builtin_amdgcn_mfma_f32_16x16x32_bf16(kf[ct][0], qf[0], sacc[ct], 0, 0, 0);
        sacc[ct] = __builtin_amdgcn_mfma_f32_16x16x32_bf16(kf[ct][1], qf[1], sacc[ct], 0, 0, 0);
      }

      // mask (last tile only) + per-lane max — already exp2-domain
      float tmax = -1e30f;
      if (kt == nkt - 1) {
        const int qg = q0 + ln;
#pragma unroll
        for (int ct = 0; ct < 4; ct++) {
          const int kvb = kv0 + ct * 16 + quad * 4;
#pragma unroll
          for (int reg = 0; reg < 4; reg++) {
            float sv = sacc[ct][reg];
            if (kvb + reg > qg) sv = -1e30f;
            sacc[ct][reg] = sv;
            tmax = fmaxf(tmax, sv);
          }
        }
      } else {
#pragma unroll
        for (int ct = 0; ct < 4; ct++)
#pragma unroll
          for (int reg = 0; reg < 4; reg++) tmax = fmaxf(tmax, sacc[ct][reg]);
      }
      tmax = fmaxf(tmax, __shfl_xor(tmax, 16, 64));
      tmax = fmaxf(tmax, __shfl_xor(tmax, 32, 64));

      // online softmax (exp2 domain)
      const float mnew = fmaxf(m, tmax);
      const float alpha = exp2f(m - mnew);
      m = mnew;
      float rsum = 0.f;
#pragma unroll
      for (int ct = 0; ct < 4; ct++) {
        u16x4 pk;
#pragma unroll
        for (int reg = 0; reg < 4; reg++) {
          const float p = exp2f(sacc[ct][reg] - m);
          rsum += p;
          pk[reg] = f32_to_bf16(p);
        }
        *(u16x4*)(Pb + ln * PSTR + ct * 16 + quad * 4) = pk;
      }
      rsum += __shfl_xor(rsum, 16, 64);
      rsum += __shfl_xor(rsum, 32, 64);
      l = l * alpha + rsum;
#pragma unroll
      for (int nt = 0; nt < 4; nt++)
#pragma unroll
        for (int reg = 0; reg < 4; reg++) oacc[nt][reg] *= alpha;

      __builtin_amdgcn_wave_barrier();

      bf16x8 pf0 = *(const bf16x8*)(Pb + ln * PSTR + quad * 8);
      bf16x8 pf1 = *(const bf16x8*)(Pb + ln * PSTR + 32 + quad * 8);

#pragma unroll
      for (int nt = 0; nt < 4; nt++) {
        oacc[nt] = __builtin_amdgcn_mfma_f32_16x16x32_bf16(vf[nt][0], pf0, oacc[nt], 0, 0, 0);
        oacc[nt] = __builtin_amdgcn_mfma_f32_16x16x32_bf16(vf[nt][1], pf1, oacc[nt], 0, 0, 0);
      }
      __builtin_amdgcn_wave_barrier();
    }

    // epilogue: O^T C-layout -> O[q][dk]
    const float inv = 1.0f / l;
    unsigned short* op = O + (long)b * S_LEN * D_MODEL + (long)(q0 + ln) * D_MODEL + h * D_HEAD;
#pragma unroll
    for (int nt = 0; nt < 4; nt++) {
      u16x4 pk;
#pragma unroll
      for (int reg = 0; reg < 4; reg++) pk[reg] = f32_to_bf16(oacc[nt][reg] * inv);
      *(u16x4*)(op + nt * 16 + quad * 4) = pk;
    }
  }
}

// ---------------------------------------------------------------------------
extern "C" void kernel_launch(void* const* d_in, const int* in_sizes, int n_in,
                              void* d_out, int out_size, void* d_ws, size_t ws_size,
                              hipStream_t stream) {
  const float* q = (const float*)d_in[0];
  const float* k = (const float*)d_in[1];
  const float* v = (const float*)d_in[2];
  // d_in[3] = causal mask (hardcoded)
  const float* w_q = (const float*)d_in[4];
  const float* b_q = (const float*)d_in[5];
  const float* w_k = (const float*)d_in[6];
  const float* b_k = (const float*)d_in[7];
  const float* w_v = (const float*)d_in[8];
  const float* b_v = (const float*)d_in[9];
  const float* w_o = (const float*)d_in[10];
  const float* b_o = (const float*)d_in[11];
  float* out = (float*)d_out;

  unsigned short* ws = (unsigned short*)d_ws;
  const long NE = (long)M_ROWS * D_MODEL;  // 4M elems
  unsigned short* Qp = ws;            //  0..8 MiB
  unsigned short* Kp = ws + NE;       //  8..16
  unsigned short* Vpt = ws + 2 * NE;  // 16..24  (transposed [D][4096])
  unsigned short* AO = ws + 3 * NE;   // 24..32
  unsigned short* Wb = ws + 4 * NE;   // 32..40  (4 x 1M bf16 weights)

  cvt_w<<<dim3(256, 4), 256, 0, stream>>>(w_q, w_k, w_v, w_o, Wb);
  qkv_gemm<<<dim3(M_ROWS / 128, GN / 128, 3), 256, 0, stream>>>(
      q, k, v, Wb, b_q, b_k, b_v, Qp, Kp, Vpt);
  attn_causal<<<dim3(2 * N_HEADS, S_LEN / 32), 64, 0, stream>>>(Qp, Kp, Vpt, AO);
  out_gemm<<<dim3(M_ROWS / 64, GN / 128), 256, 0, stream>>>(AO, Wb + 3 * (1 << 20), b_o, out);
}

// Round 5
// 284.644 us; speedup vs baseline: 1.6988x; 1.1236x over previous
//
#include <hip/hip_runtime.h>

// ---------------------------------------------------------------------------
// MultiHeadAttentionBlock: B=2, S=2048, D=1024, H=16, DK=64, causal.
// FP32 I/O; bf16 MFMA compute, fp32 accumulate.
// r5: dual-strip attention blocks (strips s and 127-s share K/V fragments ->
//     half the loads, 2x ILP); X inputs pre-converted to bf16 (ws permitting).
// ---------------------------------------------------------------------------

typedef __attribute__((ext_vector_type(8))) short bf16x8;     // 8 bf16 = 4 VGPRs
typedef __attribute__((ext_vector_type(4))) float floatx4;    // MFMA C/D
typedef __attribute__((ext_vector_type(4))) unsigned short u16x4;  // 8B packed bf16

#define S_LEN 2048
#define D_MODEL 1024
#define N_HEADS 16
#define D_HEAD 64
#define M_ROWS 4096   // B*S
#define QSCALE 0.18033688011112042f  // 0.125 * log2(e)

__device__ __forceinline__ unsigned short f32_to_bf16(float f) {
  unsigned int u = __builtin_bit_cast(unsigned int, f);
  u += 0x7FFFu + ((u >> 16) & 1u);  // RNE
  return (unsigned short)(u >> 16);
}

// ---------------------------------------------------------------------------
// fp32 -> bf16 pre-passes.
// ---------------------------------------------------------------------------
__global__ __launch_bounds__(256) void cvt_w(
    const float* __restrict__ w0, const float* __restrict__ w1,
    const float* __restrict__ w2, const float* __restrict__ w3,
    unsigned short* __restrict__ dst) {
  const int z = blockIdx.y;
  const float* src = (z == 0) ? w0 : (z == 1) ? w1 : (z == 2) ? w2 : w3;
  unsigned short* d = dst + ((long)z << 20);
  const int n4 = 1 << 18;
  for (int i = blockIdx.x * 256 + threadIdx.x; i < n4; i += gridDim.x * 256) {
    float4 f = ((const float4*)src)[i];
    u16x4 o;
    o[0] = f32_to_bf16(f.x); o[1] = f32_to_bf16(f.y);
    o[2] = f32_to_bf16(f.z); o[3] = f32_to_bf16(f.w);
    ((u16x4*)d)[i] = o;
  }
}

__global__ __launch_bounds__(256) void cvt_x(
    const float* __restrict__ x0, const float* __restrict__ x1,
    const float* __restrict__ x2, unsigned short* __restrict__ dst) {
  const int z = blockIdx.y;
  const float* src = (z == 0) ? x0 : (z == 1) ? x1 : x2;
  unsigned short* d = dst + (long)z * M_ROWS * D_MODEL;
  const int n4 = (M_ROWS * D_MODEL) / 4;  // 1M
  for (int i = blockIdx.x * 256 + threadIdx.x; i < n4; i += gridDim.x * 256) {
    float4 f = ((const float4*)src)[i];
    u16x4 o;
    o[0] = f32_to_bf16(f.x); o[1] = f32_to_bf16(f.y);
    o[2] = f32_to_bf16(f.z); o[3] = f32_to_bf16(f.w);
    ((u16x4*)d)[i] = o;
  }
}

// ---------------------------------------------------------------------------
// Fused QKV projection. z = blockIdx.z.  Y = X @ W^T + b.
// XPRE: A read from pre-converted bf16 Xb; else fp32 X with in-loop cvt.
// z=0: Y = (X Wq^T + bq) * QSCALE.  z=1: plain.  z=2: Y^T (V transposed).
// 128x128 tile, BK=32, 4 waves x (64x64).
// ---------------------------------------------------------------------------
#define GK 1024
#define GN 1024
#define LDP 40  // 32 + 8 pad; row stride 80 B

template <bool XPRE>
__global__ __launch_bounds__(256, 3) void qkv_gemm(
    const float* __restrict__ Xq, const float* __restrict__ Xk, const float* __restrict__ Xv,
    const unsigned short* __restrict__ Xb,  // bf16, 3 x NE (XPRE only)
    const unsigned short* __restrict__ Wb,  // bf16, 4 x 1M: [wq|wk|wv|wo]
    const float* __restrict__ bq, const float* __restrict__ bk, const float* __restrict__ bv,
    unsigned short* __restrict__ Yq, unsigned short* __restrict__ Yk,
    unsigned short* __restrict__ Yvt) {
  __shared__ __align__(16) unsigned short As[128 * LDP];
  __shared__ __align__(16) unsigned short Bs[128 * LDP];

  const int z = blockIdx.z;
  const unsigned short* W = Wb + ((long)z << 20);
  const float* bias = (z == 0) ? bq : ((z == 1) ? bk : bv);

  const int r0 = blockIdx.x * 128;
  const int n0 = blockIdx.y * 128;
  const int tid = threadIdx.x;
  const int lane = tid & 63;
  const int wave = tid >> 6;
  const int quad = lane >> 4;
  const int ln = lane & 15;
  const int wm = (wave >> 1) * 64;
  const int wn = (wave & 1) * 64;

  floatx4 acc[4][4];
#pragma unroll
  for (int i = 0; i < 4; i++)
#pragma unroll
    for (int j = 0; j < 4; j++) acc[i][j] = (floatx4){0.f, 0.f, 0.f, 0.f};

  const int srow = tid >> 1;
  const int scol = (tid & 1) * 16;
  unsigned short* Asw = As + srow * LDP + scol;
  unsigned short* Bsw = Bs + srow * LDP + scol;
  const unsigned short* Bp = W + (long)(n0 + srow) * GK + scol;
  const float* ApF = nullptr;
  const unsigned short* ApH = nullptr;
  if constexpr (XPRE) {
    ApH = Xb + (long)z * M_ROWS * D_MODEL + (long)(r0 + srow) * GK + scol;
  } else {
    const float* X = (z == 0) ? Xq : ((z == 1) ? Xk : Xv);
    ApF = X + (long)(r0 + srow) * GK + scol;
  }

  for (int k0 = 0; k0 < GK; k0 += 32) {
    float4 b0 = *(const float4*)(Bp + k0);
    float4 b1 = *(const float4*)(Bp + k0 + 8);
    float4 a0, a1;
    if constexpr (XPRE) {
      a0 = *(const float4*)(ApH + k0);
      a1 = *(const float4*)(ApH + k0 + 8);
    } else {
      unsigned short ua[16] __attribute__((aligned(16)));
      float fa[16] __attribute__((aligned(16)));
      *(float4*)(fa + 0)  = *(const float4*)(ApF + k0 + 0);
      *(float4*)(fa + 4)  = *(const float4*)(ApF + k0 + 4);
      *(float4*)(fa + 8)  = *(const float4*)(ApF + k0 + 8);
      *(float4*)(fa + 12) = *(const float4*)(ApF + k0 + 12);
#pragma unroll
      for (int j = 0; j < 16; j++) ua[j] = f32_to_bf16(fa[j]);
      a0 = *(float4*)(ua);
      a1 = *(float4*)(ua + 8);
    }
    __syncthreads();
    *(float4*)(Asw) = a0;
    *(float4*)(Asw + 8) = a1;
    *(float4*)(Bsw) = b0;
    *(float4*)(Bsw + 8) = b1;
    __syncthreads();

    bf16x8 af[4], bfr[4];
#pragma unroll
    for (int mt = 0; mt < 4; mt++)
      af[mt] = *(const bf16x8*)(As + (wm + mt * 16 + ln) * LDP + quad * 8);
#pragma unroll
    for (int nt = 0; nt < 4; nt++)
      bfr[nt] = *(const bf16x8*)(Bs + (wn + nt * 16 + ln) * LDP + quad * 8);
#pragma unroll
    for (int mt = 0; mt < 4; mt++)
#pragma unroll
      for (int nt = 0; nt < 4; nt++)
        acc[mt][nt] = __builtin_amdgcn_mfma_f32_16x16x32_bf16(af[mt], bfr[nt], acc[mt][nt], 0, 0, 0);
  }

#pragma unroll
  for (int nt = 0; nt < 4; nt++) {
    const int n = n0 + wn + nt * 16 + ln;
    const float bv = bias[n];
#pragma unroll
    for (int mt = 0; mt < 4; mt++) {
      const int r = r0 + wm + mt * 16 + quad * 4;
      if (z == 2) {  // V^T: Yvt[n][r..r+3]
        u16x4 pk;
#pragma unroll
        for (int reg = 0; reg < 4; reg++) pk[reg] = f32_to_bf16(acc[mt][nt][reg] + bv);
        *(u16x4*)(Yvt + (long)n * M_ROWS + r) = pk;
      } else if (z == 0) {  // Q pre-scaled for exp2-domain softmax
#pragma unroll
        for (int reg = 0; reg < 4; reg++)
          Yq[(long)(r + reg) * GN + n] = f32_to_bf16((acc[mt][nt][reg] + bv) * QSCALE);
      } else {
#pragma unroll
        for (int reg = 0; reg < 4; reg++)
          Yk[(long)(r + reg) * GN + n] = f32_to_bf16(acc[mt][nt][reg] + bv);
      }
    }
  }
}

// ---------------------------------------------------------------------------
// Out projection: Y fp32 = AO(bf16) @ Wo(bf16)^T + b.  64x128 tile, 512 blocks.
// ---------------------------------------------------------------------------
__global__ __launch_bounds__(256, 3) void out_gemm(
    const unsigned short* __restrict__ X,
    const unsigned short* __restrict__ W,
    const float* __restrict__ bias,
    float* __restrict__ Y) {
  __shared__ __align__(16) unsigned short As[64 * LDP];
  __shared__ __align__(16) unsigned short Bs[128 * LDP];

  const int r0 = blockIdx.x * 64;
  const int n0 = blockIdx.y * 128;
  const int tid = threadIdx.x;
  const int lane = tid & 63;
  const int wave = tid >> 6;
  const int quad = lane >> 4;
  const int ln = lane & 15;
  const int wm = (wave >> 1) * 32;
  const int wn = (wave & 1) * 64;

  floatx4 acc[2][4];
#pragma unroll
  for (int i = 0; i < 2; i++)
#pragma unroll
    for (int j = 0; j < 4; j++) acc[i][j] = (floatx4){0.f, 0.f, 0.f, 0.f};

  const int arow = tid >> 2;
  const int acol = (tid & 3) * 8;
  const unsigned short* Ap = X + (long)(r0 + arow) * GK + acol;
  unsigned short* Asw = As + arow * LDP + acol;
  const int brow = tid >> 1;
  const int bcol = (tid & 1) * 16;
  const unsigned short* Bp = W + (long)(n0 + brow) * GK + bcol;
  unsigned short* Bsw = Bs + brow * LDP + bcol;

  for (int k0 = 0; k0 < GK; k0 += 32) {
    float4 a0 = *(const float4*)(Ap + k0);
    float4 b0 = *(const float4*)(Bp + k0);
    float4 b1 = *(const float4*)(Bp + k0 + 8);
    __syncthreads();
    *(float4*)(Asw) = a0;
    *(float4*)(Bsw) = b0;
    *(float4*)(Bsw + 8) = b1;
    __syncthreads();

    bf16x8 af[2], bfr[4];
#pragma unroll
    for (int mt = 0; mt < 2; mt++)
      af[mt] = *(const bf16x8*)(As + (wm + mt * 16 + ln) * LDP + quad * 8);
#pragma unroll
    for (int nt = 0; nt < 4; nt++)
      bfr[nt] = *(const bf16x8*)(Bs + (wn + nt * 16 + ln) * LDP + quad * 8);
#pragma unroll
    for (int mt = 0; mt < 2; mt++)
#pragma unroll
      for (int nt = 0; nt < 4; nt++)
        acc[mt][nt] = __builtin_amdgcn_mfma_f32_16x16x32_bf16(af[mt], bfr[nt], acc[mt][nt], 0, 0, 0);
  }

#pragma unroll
  for (int nt = 0; nt < 4; nt++) {
    const int n = n0 + wn + nt * 16 + ln;
    const float bv = bias[n];
#pragma unroll
    for (int mt = 0; mt < 2; mt++) {
      const int r = r0 + wm + mt * 16 + quad * 4;
#pragma unroll
      for (int reg = 0; reg < 4; reg++)
        Y[(long)(r + reg) * GN + n] = acc[mt][nt][reg] + bv;
    }
  }
}

// ---------------------------------------------------------------------------
// Dual-strip per-wave flash attention (causal), exp2-domain (Q pre-scaled).
// One 64-thread block = one wave, owns strips s1=pr and s2=127-pr CONCURRENTLY:
// both iterate KV tiles from kt=0, so each loaded K/V fragment set feeds both
// strips (half the loads, 2x MFMA + two independent softmax chains for ILP).
// S^T = K Q^T (C-layout row=kv, col=q); O^T = V^T P^T (P^T via per-wave LDS).
// ---------------------------------------------------------------------------
#define PSTR 72

__global__ __launch_bounds__(64, 2) void attn_causal(
    const unsigned short* __restrict__ Q,   // bf16 [B,S,D], pre-scaled
    const unsigned short* __restrict__ K,   // bf16 [B,S,D]
    const unsigned short* __restrict__ Vt,  // bf16 [D][4096]
    unsigned short* __restrict__ O) {       // bf16 [B,S,D]
  __shared__ __align__(16) unsigned short PbA[16 * PSTR];
  __shared__ __align__(16) unsigned short PbB[16 * PSTR];

  const int bh = blockIdx.x;   // 0..31
  const int pr = blockIdx.y;   // 0..63
  const int b = bh >> 4;
  const int h = bh & 15;

  const int lane = threadIdx.x;
  const int quad = lane >> 4;
  const int ln = lane & 15;

  const int s1 = pr, s2 = 127 - pr;
  const int q0A = s1 * 16, q0B = s2 * 16;
  const int nkt1 = (s1 >> 2) + 1;  // 1..16
  const int nkt2 = (s2 >> 2) + 1;  // 17..32

  const unsigned short* Qb = Q + (long)b * S_LEN * D_MODEL + h * D_HEAD;
  const unsigned short* Kb = K + (long)b * S_LEN * D_MODEL + h * D_HEAD;
  const unsigned short* Vb = Vt + (long)h * D_HEAD * M_ROWS + b * S_LEN;

  bf16x8 qfA[2], qfB[2];
  qfA[0] = *(const bf16x8*)(Qb + (long)(q0A + ln) * D_MODEL + quad * 8);
  qfA[1] = *(const bf16x8*)(Qb + (long)(q0A + ln) * D_MODEL + 32 + quad * 8);
  qfB[0] = *(const bf16x8*)(Qb + (long)(q0B + ln) * D_MODEL + quad * 8);
  qfB[1] = *(const bf16x8*)(Qb + (long)(q0B + ln) * D_MODEL + 32 + quad * 8);

  float mA = -1e30f, lA = 0.f, mB = -1e30f, lB = 0.f;
  floatx4 oA[4], oB[4];
#pragma unroll
  for (int nt = 0; nt < 4; nt++) {
    oA[nt] = (floatx4){0.f, 0.f, 0.f, 0.f};
    oB[nt] = (floatx4){0.f, 0.f, 0.f, 0.f};
  }

#pragma unroll 1
  for (int kt = 0; kt < nkt2; kt++) {
    const int kv0 = kt * 64;
    const bool aAct = (kt < nkt1);

    // ---- shared K/V fragment loads (16 B / lane each)
    bf16x8 kf[4][2], vf[4][2];
#pragma unroll
    for (int ct = 0; ct < 4; ct++) {
      const unsigned short* kp = Kb + (long)(kv0 + ct * 16 + ln) * D_MODEL + quad * 8;
      kf[ct][0] = *(const bf16x8*)(kp);
      kf[ct][1] = *(const bf16x8*)(kp + 32);
    }
#pragma unroll
    for (int nt = 0; nt < 4; nt++) {
      const unsigned short* vp = Vb + (long)(nt * 16 + ln) * M_ROWS + kv0 + quad * 8;
      vf[nt][0] = *(const bf16x8*)(vp);
      vf[nt][1] = *(const bf16x8*)(vp + 32);
    }

    // ---- S^T = K Q^T for both strips
    floatx4 sB[4], sA[4];
#pragma unroll
    for (int ct = 0; ct < 4; ct++) {
      sB[ct] = (floatx4){0.f, 0.f, 0.f, 0.f};
      sB[ct] = __builtin_amdgcn_mfma_f32_16x16x32_bf16(kf[ct][0], qfB[0], sB[ct], 0, 0, 0);
      sB[ct] = __builtin_amdgcn_mfma_f32_16x16x32_bf16(kf[ct][1], qfB[1], sB[ct], 0, 0, 0);
    }
    if (aAct) {
#pragma unroll
      for (int ct = 0; ct < 4; ct++) {
        sA[ct] = (floatx4){0.f, 0.f, 0.f, 0.f};
        sA[ct] = __builtin_amdgcn_mfma_f32_16x16x32_bf16(kf[ct][0], qfA[0], sA[ct], 0, 0, 0);
        sA[ct] = __builtin_amdgcn_mfma_f32_16x16x32_bf16(kf[ct][1], qfA[1], sA[ct], 0, 0, 0);
      }
    }

    // ---- softmax B
    {
      float tmax = -1e30f;
      if (kt == nkt2 - 1) {
        const int qg = q0B + ln;
#pragma unroll
        for (int ct = 0; ct < 4; ct++) {
          const int kvb = kv0 + ct * 16 + quad * 4;
#pragma unroll
          for (int reg = 0; reg < 4; reg++) {
            float sv = sB[ct][reg];
            if (kvb + reg > qg) sv = -1e30f;
            sB[ct][reg] = sv;
            tmax = fmaxf(tmax, sv);
          }
        }
      } else {
#pragma unroll
        for (int ct = 0; ct < 4; ct++)
#pragma unroll
          for (int reg = 0; reg < 4; reg++) tmax = fmaxf(tmax, sB[ct][reg]);
      }
      tmax = fmaxf(tmax, __shfl_xor(tmax, 16, 64));
      tmax = fmaxf(tmax, __shfl_xor(tmax, 32, 64));
      const float mnew = fmaxf(mB, tmax);
      const float alpha = exp2f(mB - mnew);
      mB = mnew;
      float rsum = 0.f;
#pragma unroll
      for (int ct = 0; ct < 4; ct++) {
        u16x4 pk;
#pragma unroll
        for (int reg = 0; reg < 4; reg++) {
          const float p = exp2f(sB[ct][reg] - mB);
          rsum += p;
          pk[reg] = f32_to_bf16(p);
        }
        *(u16x4*)(PbB + ln * PSTR + ct * 16 + quad * 4) = pk;
      }
      rsum += __shfl_xor(rsum, 16, 64);
      rsum += __shfl_xor(rsum, 32, 64);
      lB = lB * alpha + rsum;
#pragma unroll
      for (int nt = 0; nt < 4; nt++)
#pragma unroll
        for (int reg = 0; reg < 4; reg++) oB[nt][reg] *= alpha;
    }

    // ---- softmax A (independent chain -> ILP)
    if (aAct) {
      float tmax = -1e30f;
      if (kt == nkt1 - 1) {
        const int qg = q0A + ln;
#pragma unroll
        for (int ct = 0; ct < 4; ct++) {
          const int kvb = kv0 + ct * 16 + quad * 4;
#pragma unroll
          for (int reg = 0; reg < 4; reg++) {
            float sv = sA[ct][reg];
            if (kvb + reg > qg) sv = -1e30f;
            sA[ct][reg] = sv;
            tmax = fmaxf(tmax, sv);
          }
        }
      } else {
#pragma unroll
        for (int ct = 0; ct < 4; ct++)
#pragma unroll
          for (int reg = 0; reg < 4; reg++) tmax = fmaxf(tmax, sA[ct][reg]);
      }
      tmax = fmaxf(tmax, __shfl_xor(tmax, 16, 64));
      tmax = fmaxf(tmax, __shfl_xor(tmax, 32, 64));
      const float mnew = fmaxf(mA, tmax);
      const float alpha = exp2f(mA - mnew);
      mA = mnew;
      float rsum = 0.f;
#pragma unroll
      for (int ct = 0; ct < 4; ct++) {
        u16x4 pk;
#pragma unroll
        for (int reg = 0; reg < 4; reg++) {
          const float p = exp2f(sA[ct][reg] - mA);
          rsum += p;
          pk[reg] = f32_to_bf16(p);
        }
        *(u16x4*)(PbA + ln * PSTR + ct * 16 + quad * 4) = pk;
      }
      rsum += __shfl_xor(rsum, 16, 64);
      rsum += __shfl_xor(rsum, 32, 64);
      lA = lA * alpha + rsum;
#pragma unroll
      for (int nt = 0; nt < 4; nt++)
#pragma unroll
        for (int reg = 0; reg < 4; reg++) oA[nt][reg] *= alpha;
    }

    __builtin_amdgcn_wave_barrier();

    // ---- O^T += V^T P^T (shared vf)
    {
      bf16x8 p0 = *(const bf16x8*)(PbB + ln * PSTR + quad * 8);
      bf16x8 p1 = *(const bf16x8*)(PbB + ln * PSTR + 32 + quad * 8);
#pragma unroll
      for (int nt = 0; nt < 4; nt++) {
        oB[nt] = __builtin_amdgcn_mfma_f32_16x16x32_bf16(vf[nt][0], p0, oB[nt], 0, 0, 0);
        oB[nt] = __builtin_amdgcn_mfma_f32_16x16x32_bf16(vf[nt][1], p1, oB[nt], 0, 0, 0);
      }
    }
    if (aAct) {
      bf16x8 p0 = *(const bf16x8*)(PbA + ln * PSTR + quad * 8);
      bf16x8 p1 = *(const bf16x8*)(PbA + ln * PSTR + 32 + quad * 8);
#pragma unroll
      for (int nt = 0; nt < 4; nt++) {
        oA[nt] = __builtin_amdgcn_mfma_f32_16x16x32_bf16(vf[nt][0], p0, oA[nt], 0, 0, 0);
        oA[nt] = __builtin_amdgcn_mfma_f32_16x16x32_bf16(vf[nt][1], p1, oA[nt], 0, 0, 0);
      }
    }
    __builtin_amdgcn_wave_barrier();
  }

  // ---- epilogues: O^T C-layout -> O[q][dk]
  {
    const float inv = 1.0f / lA;
    unsigned short* op = O + (long)b * S_LEN * D_MODEL + (long)(q0A + ln) * D_MODEL + h * D_HEAD;
#pragma unroll
    for (int nt = 0; nt < 4; nt++) {
      u16x4 pk;
#pragma unroll
      for (int reg = 0; reg < 4; reg++) pk[reg] = f32_to_bf16(oA[nt][reg] * inv);
      *(u16x4*)(op + nt * 16 + quad * 4) = pk;
    }
  }
  {
    const float inv = 1.0f / lB;
    unsigned short* op = O + (long)b * S_LEN * D_MODEL + (long)(q0B + ln) * D_MODEL + h * D_HEAD;
#pragma unroll
    for (int nt = 0; nt < 4; nt++) {
      u16x4 pk;
#pragma unroll
      for (int reg = 0; reg < 4; reg++) pk[reg] = f32_to_bf16(oB[nt][reg] * inv);
      *(u16x4*)(op + nt * 16 + quad * 4) = pk;
    }
  }
}

// ---------------------------------------------------------------------------
extern "C" void kernel_launch(void* const* d_in, const int* in_sizes, int n_in,
                              void* d_out, int out_size, void* d_ws, size_t ws_size,
                              hipStream_t stream) {
  const float* q = (const float*)d_in[0];
  const float* k = (const float*)d_in[1];
  const float* v = (const float*)d_in[2];
  // d_in[3] = causal mask (hardcoded)
  const float* w_q = (const float*)d_in[4];
  const float* b_q = (const float*)d_in[5];
  const float* w_k = (const float*)d_in[6];
  const float* b_k = (const float*)d_in[7];
  const float* w_v = (const float*)d_in[8];
  const float* b_v = (const float*)d_in[9];
  const float* w_o = (const float*)d_in[10];
  const float* b_o = (const float*)d_in[11];
  float* out = (float*)d_out;

  unsigned short* ws = (unsigned short*)d_ws;
  const long NE = (long)M_ROWS * D_MODEL;  // 4M elems = 8 MiB bf16
  const bool xpre = (ws_size >= (size_t)7 * NE * sizeof(unsigned short));  // 56 MiB

  unsigned short *Qp, *Kp, *Vpt, *AO, *Wb, *Xb;
  if (xpre) {
    Qp = ws;             // [0, NE)
    Kp = ws + NE;        // [NE, 2NE)
    Vpt = ws + 2 * NE;   // [2NE, 3NE)
    Wb = ws + 3 * NE;    // [3NE, 4NE)   4 x 1M bf16 weights
    Xb = ws + 4 * NE;    // [4NE, 7NE)   3 x NE bf16 inputs
    AO = ws + 4 * NE;    // aliases Xb_q (dead after qkv_gemm)
  } else {
    Qp = ws;
    Kp = ws + NE;
    Vpt = ws + 2 * NE;
    AO = ws + 3 * NE;
    Wb = ws + 4 * NE;
    Xb = nullptr;
  }

  cvt_w<<<dim3(256, 4), 256, 0, stream>>>(w_q, w_k, w_v, w_o, Wb);
  if (xpre) {
    cvt_x<<<dim3(512, 3), 256, 0, stream>>>(q, k, v, Xb);
    qkv_gemm<true><<<dim3(M_ROWS / 128, GN / 128, 3), 256, 0, stream>>>(
        q, k, v, Xb, Wb, b_q, b_k, b_v, Qp, Kp, Vpt);
  } else {
    qkv_gemm<false><<<dim3(M_ROWS / 128, GN / 128, 3), 256, 0, stream>>>(
        q, k, v, nullptr, Wb, b_q, b_k, b_v, Qp, Kp, Vpt);
  }
  attn_causal<<<dim3(2 * N_HEADS, 64), 64, 0, stream>>>(Qp, Kp, Vpt, AO);
  out_gemm<<<dim3(M_ROWS / 64, GN / 128), 256, 0, stream>>>(AO, Wb + 3 * (1 << 20), b_o, out);
}

// Round 6
// 283.076 us; speedup vs baseline: 1.7082x; 1.0055x over previous
//
#include <hip/hip_runtime.h>

// ---------------------------------------------------------------------------
// MultiHeadAttentionBlock: B=2, S=2048, D=1024, H=16, DK=64, causal.
// FP32 I/O; bf16 MFMA compute, fp32 accumulate.
// r6: attention K/V register double-buffer prefetch (hide load latency at the
//     grid-capped 2 waves/SIMD); GEMMs BK=64 (half the barriers).
// ---------------------------------------------------------------------------

typedef __attribute__((ext_vector_type(8))) short bf16x8;     // 8 bf16 = 4 VGPRs
typedef __attribute__((ext_vector_type(4))) float floatx4;    // MFMA C/D
typedef __attribute__((ext_vector_type(4))) unsigned short u16x4;  // 8B packed bf16

#define S_LEN 2048
#define D_MODEL 1024
#define N_HEADS 16
#define D_HEAD 64
#define M_ROWS 4096   // B*S
#define QSCALE 0.18033688011112042f  // 0.125 * log2(e)

__device__ __forceinline__ unsigned short f32_to_bf16(float f) {
  unsigned int u = __builtin_bit_cast(unsigned int, f);
  u += 0x7FFFu + ((u >> 16) & 1u);  // RNE
  return (unsigned short)(u >> 16);
}

// ---------------------------------------------------------------------------
// fp32 -> bf16 pre-passes.
// ---------------------------------------------------------------------------
__global__ __launch_bounds__(256) void cvt_w(
    const float* __restrict__ w0, const float* __restrict__ w1,
    const float* __restrict__ w2, const float* __restrict__ w3,
    unsigned short* __restrict__ dst) {
  const int z = blockIdx.y;
  const float* src = (z == 0) ? w0 : (z == 1) ? w1 : (z == 2) ? w2 : w3;
  unsigned short* d = dst + ((long)z << 20);
  const int n4 = 1 << 18;
  for (int i = blockIdx.x * 256 + threadIdx.x; i < n4; i += gridDim.x * 256) {
    float4 f = ((const float4*)src)[i];
    u16x4 o;
    o[0] = f32_to_bf16(f.x); o[1] = f32_to_bf16(f.y);
    o[2] = f32_to_bf16(f.z); o[3] = f32_to_bf16(f.w);
    ((u16x4*)d)[i] = o;
  }
}

__global__ __launch_bounds__(256) void cvt_x(
    const float* __restrict__ x0, const float* __restrict__ x1,
    const float* __restrict__ x2, unsigned short* __restrict__ dst) {
  const int z = blockIdx.y;
  const float* src = (z == 0) ? x0 : (z == 1) ? x1 : x2;
  unsigned short* d = dst + (long)z * M_ROWS * D_MODEL;
  const int n4 = (M_ROWS * D_MODEL) / 4;  // 1M
  for (int i = blockIdx.x * 256 + threadIdx.x; i < n4; i += gridDim.x * 256) {
    float4 f = ((const float4*)src)[i];
    u16x4 o;
    o[0] = f32_to_bf16(f.x); o[1] = f32_to_bf16(f.y);
    o[2] = f32_to_bf16(f.z); o[3] = f32_to_bf16(f.w);
    ((u16x4*)d)[i] = o;
  }
}

// ---------------------------------------------------------------------------
// Fused QKV projection. z = blockIdx.z.  Y = X @ W^T + b.
// 128x128 tile, BK=64, 4 waves x (64x64), 32 MFMA per barrier-pair.
// z=0: Y = (X Wq^T + bq) * QSCALE.  z=1: plain.  z=2: Y^T (V transposed).
// ---------------------------------------------------------------------------
#define GK 1024
#define GN 1024
#define LDP 72  // 64 + 8 pad; row stride 144 B (16B-aligned)

template <bool XPRE>
__global__ __launch_bounds__(256, 3) void qkv_gemm(
    const float* __restrict__ Xq, const float* __restrict__ Xk, const float* __restrict__ Xv,
    const unsigned short* __restrict__ Xb,  // bf16, 3 x NE (XPRE only)
    const unsigned short* __restrict__ Wb,  // bf16, 4 x 1M: [wq|wk|wv|wo]
    const float* __restrict__ bq, const float* __restrict__ bk, const float* __restrict__ bv,
    unsigned short* __restrict__ Yq, unsigned short* __restrict__ Yk,
    unsigned short* __restrict__ Yvt) {
  __shared__ __align__(16) unsigned short As[128 * LDP];
  __shared__ __align__(16) unsigned short Bs[128 * LDP];

  const int z = blockIdx.z;
  const unsigned short* W = Wb + ((long)z << 20);
  const float* bias = (z == 0) ? bq : ((z == 1) ? bk : bv);

  const int r0 = blockIdx.x * 128;
  const int n0 = blockIdx.y * 128;
  const int tid = threadIdx.x;
  const int lane = tid & 63;
  const int wave = tid >> 6;
  const int quad = lane >> 4;
  const int ln = lane & 15;
  const int wm = (wave >> 1) * 64;
  const int wn = (wave & 1) * 64;

  floatx4 acc[4][4];
#pragma unroll
  for (int i = 0; i < 4; i++)
#pragma unroll
    for (int j = 0; j < 4; j++) acc[i][j] = (floatx4){0.f, 0.f, 0.f, 0.f};

  // staging: 128 rows x 64 k / 256 threads = 32 elems each
  const int srow = tid >> 1;
  const int scol = (tid & 1) * 32;
  unsigned short* Asw = As + srow * LDP + scol;
  unsigned short* Bsw = Bs + srow * LDP + scol;
  const unsigned short* Bp = W + (long)(n0 + srow) * GK + scol;
  const float* ApF = nullptr;
  const unsigned short* ApH = nullptr;
  if constexpr (XPRE) {
    ApH = Xb + (long)z * M_ROWS * D_MODEL + (long)(r0 + srow) * GK + scol;
  } else {
    const float* X = (z == 0) ? Xq : ((z == 1) ? Xk : Xv);
    ApF = X + (long)(r0 + srow) * GK + scol;
  }

  for (int k0 = 0; k0 < GK; k0 += 64) {
    float4 b0 = *(const float4*)(Bp + k0);
    float4 b1 = *(const float4*)(Bp + k0 + 8);
    float4 b2 = *(const float4*)(Bp + k0 + 16);
    float4 b3 = *(const float4*)(Bp + k0 + 24);
    float4 a0, a1, a2, a3;
    if constexpr (XPRE) {
      a0 = *(const float4*)(ApH + k0);
      a1 = *(const float4*)(ApH + k0 + 8);
      a2 = *(const float4*)(ApH + k0 + 16);
      a3 = *(const float4*)(ApH + k0 + 24);
    } else {
      unsigned short ua[32] __attribute__((aligned(16)));
      float fa[32] __attribute__((aligned(16)));
#pragma unroll
      for (int c = 0; c < 8; c++)
        *(float4*)(fa + c * 4) = *(const float4*)(ApF + k0 + c * 4);
#pragma unroll
      for (int j = 0; j < 32; j++) ua[j] = f32_to_bf16(fa[j]);
      a0 = *(float4*)(ua); a1 = *(float4*)(ua + 8);
      a2 = *(float4*)(ua + 16); a3 = *(float4*)(ua + 24);
    }
    __syncthreads();
    *(float4*)(Asw) = a0;      *(float4*)(Asw + 8) = a1;
    *(float4*)(Asw + 16) = a2; *(float4*)(Asw + 24) = a3;
    *(float4*)(Bsw) = b0;      *(float4*)(Bsw + 8) = b1;
    *(float4*)(Bsw + 16) = b2; *(float4*)(Bsw + 24) = b3;
    __syncthreads();

#pragma unroll
    for (int ks = 0; ks < 64; ks += 32) {
      bf16x8 af[4], bfr[4];
#pragma unroll
      for (int mt = 0; mt < 4; mt++)
        af[mt] = *(const bf16x8*)(As + (wm + mt * 16 + ln) * LDP + ks + quad * 8);
#pragma unroll
      for (int nt = 0; nt < 4; nt++)
        bfr[nt] = *(const bf16x8*)(Bs + (wn + nt * 16 + ln) * LDP + ks + quad * 8);
#pragma unroll
      for (int mt = 0; mt < 4; mt++)
#pragma unroll
        for (int nt = 0; nt < 4; nt++)
          acc[mt][nt] = __builtin_amdgcn_mfma_f32_16x16x32_bf16(af[mt], bfr[nt], acc[mt][nt], 0, 0, 0);
    }
  }

#pragma unroll
  for (int nt = 0; nt < 4; nt++) {
    const int n = n0 + wn + nt * 16 + ln;
    const float bv = bias[n];
#pragma unroll
    for (int mt = 0; mt < 4; mt++) {
      const int r = r0 + wm + mt * 16 + quad * 4;
      if (z == 2) {  // V^T: Yvt[n][r..r+3]
        u16x4 pk;
#pragma unroll
        for (int reg = 0; reg < 4; reg++) pk[reg] = f32_to_bf16(acc[mt][nt][reg] + bv);
        *(u16x4*)(Yvt + (long)n * M_ROWS + r) = pk;
      } else if (z == 0) {  // Q pre-scaled for exp2-domain softmax
#pragma unroll
        for (int reg = 0; reg < 4; reg++)
          Yq[(long)(r + reg) * GN + n] = f32_to_bf16((acc[mt][nt][reg] + bv) * QSCALE);
      } else {
#pragma unroll
        for (int reg = 0; reg < 4; reg++)
          Yk[(long)(r + reg) * GN + n] = f32_to_bf16(acc[mt][nt][reg] + bv);
      }
    }
  }
}

// ---------------------------------------------------------------------------
// Out projection: Y fp32 = AO(bf16) @ Wo(bf16)^T + b.  64x128 tile, BK=64.
// ---------------------------------------------------------------------------
__global__ __launch_bounds__(256, 3) void out_gemm(
    const unsigned short* __restrict__ X,
    const unsigned short* __restrict__ W,
    const float* __restrict__ bias,
    float* __restrict__ Y) {
  __shared__ __align__(16) unsigned short As[64 * LDP];
  __shared__ __align__(16) unsigned short Bs[128 * LDP];

  const int r0 = blockIdx.x * 64;
  const int n0 = blockIdx.y * 128;
  const int tid = threadIdx.x;
  const int lane = tid & 63;
  const int wave = tid >> 6;
  const int quad = lane >> 4;
  const int ln = lane & 15;
  const int wm = (wave >> 1) * 32;
  const int wn = (wave & 1) * 64;

  floatx4 acc[2][4];
#pragma unroll
  for (int i = 0; i < 2; i++)
#pragma unroll
    for (int j = 0; j < 4; j++) acc[i][j] = (floatx4){0.f, 0.f, 0.f, 0.f};

  // A staging: 64x64 / 256 thr = 16 elems; B: 128x64 / 256 thr = 32 elems
  const int arow = tid >> 2;
  const int acol = (tid & 3) * 16;
  const unsigned short* Ap = X + (long)(r0 + arow) * GK + acol;
  unsigned short* Asw = As + arow * LDP + acol;
  const int brow = tid >> 1;
  const int bcol = (tid & 1) * 32;
  const unsigned short* Bp = W + (long)(n0 + brow) * GK + bcol;
  unsigned short* Bsw = Bs + brow * LDP + bcol;

  for (int k0 = 0; k0 < GK; k0 += 64) {
    float4 a0 = *(const float4*)(Ap + k0);
    float4 a1 = *(const float4*)(Ap + k0 + 8);
    float4 b0 = *(const float4*)(Bp + k0);
    float4 b1 = *(const float4*)(Bp + k0 + 8);
    float4 b2 = *(const float4*)(Bp + k0 + 16);
    float4 b3 = *(const float4*)(Bp + k0 + 24);
    __syncthreads();
    *(float4*)(Asw) = a0;      *(float4*)(Asw + 8) = a1;
    *(float4*)(Bsw) = b0;      *(float4*)(Bsw + 8) = b1;
    *(float4*)(Bsw + 16) = b2; *(float4*)(Bsw + 24) = b3;
    __syncthreads();

#pragma unroll
    for (int ks = 0; ks < 64; ks += 32) {
      bf16x8 af[2], bfr[4];
#pragma unroll
      for (int mt = 0; mt < 2; mt++)
        af[mt] = *(const bf16x8*)(As + (wm + mt * 16 + ln) * LDP + ks + quad * 8);
#pragma unroll
      for (int nt = 0; nt < 4; nt++)
        bfr[nt] = *(const bf16x8*)(Bs + (wn + nt * 16 + ln) * LDP + ks + quad * 8);
#pragma unroll
      for (int mt = 0; mt < 2; mt++)
#pragma unroll
        for (int nt = 0; nt < 4; nt++)
          acc[mt][nt] = __builtin_amdgcn_mfma_f32_16x16x32_bf16(af[mt], bfr[nt], acc[mt][nt], 0, 0, 0);
    }
  }

#pragma unroll
  for (int nt = 0; nt < 4; nt++) {
    const int n = n0 + wn + nt * 16 + ln;
    const float bv = bias[n];
#pragma unroll
    for (int mt = 0; mt < 2; mt++) {
      const int r = r0 + wm + mt * 16 + quad * 4;
#pragma unroll
      for (int reg = 0; reg < 4; reg++)
        Y[(long)(r + reg) * GN + n] = acc[mt][nt][reg] + bv;
    }
  }
}

// ---------------------------------------------------------------------------
// Dual-strip per-wave flash attention (causal), exp2-domain, with register
// double-buffered K/V prefetch: iter kt+1's 16 fragment loads issue before
// iter kt's compute, hiding L2/HBM latency at the grid-capped 2 waves/SIMD.
// ---------------------------------------------------------------------------
#define PSTR 72

__global__ __launch_bounds__(64, 2) void attn_causal(
    const unsigned short* __restrict__ Q,   // bf16 [B,S,D], pre-scaled
    const unsigned short* __restrict__ K,   // bf16 [B,S,D]
    const unsigned short* __restrict__ Vt,  // bf16 [D][4096]
    unsigned short* __restrict__ O) {       // bf16 [B,S,D]
  __shared__ __align__(16) unsigned short PbA[16 * PSTR];
  __shared__ __align__(16) unsigned short PbB[16 * PSTR];

  const int bh = blockIdx.x;   // 0..31
  const int pr = blockIdx.y;   // 0..63
  const int b = bh >> 4;
  const int h = bh & 15;

  const int lane = threadIdx.x;
  const int quad = lane >> 4;
  const int ln = lane & 15;

  const int s1 = pr, s2 = 127 - pr;
  const int q0A = s1 * 16, q0B = s2 * 16;
  const int nkt1 = (s1 >> 2) + 1;  // 1..16
  const int nkt2 = (s2 >> 2) + 1;  // 17..32

  const unsigned short* Qb = Q + (long)b * S_LEN * D_MODEL + h * D_HEAD;
  const unsigned short* Kb = K + (long)b * S_LEN * D_MODEL + h * D_HEAD;
  const unsigned short* Vb = Vt + (long)h * D_HEAD * M_ROWS + b * S_LEN;

  bf16x8 qfA[2], qfB[2];
  qfA[0] = *(const bf16x8*)(Qb + (long)(q0A + ln) * D_MODEL + quad * 8);
  qfA[1] = *(const bf16x8*)(Qb + (long)(q0A + ln) * D_MODEL + 32 + quad * 8);
  qfB[0] = *(const bf16x8*)(Qb + (long)(q0B + ln) * D_MODEL + quad * 8);
  qfB[1] = *(const bf16x8*)(Qb + (long)(q0B + ln) * D_MODEL + 32 + quad * 8);

  float mA = -1e30f, lA = 0.f, mB = -1e30f, lB = 0.f;
  floatx4 oA[4], oB[4];
#pragma unroll
  for (int nt = 0; nt < 4; nt++) {
    oA[nt] = (floatx4){0.f, 0.f, 0.f, 0.f};
    oB[nt] = (floatx4){0.f, 0.f, 0.f, 0.f};
  }

  auto loadKV = [&](bf16x8 (&kf)[4][2], bf16x8 (&vf)[4][2], int kt) {
    const int kv0 = kt * 64;
#pragma unroll
    for (int ct = 0; ct < 4; ct++) {
      const unsigned short* kp = Kb + (long)(kv0 + ct * 16 + ln) * D_MODEL + quad * 8;
      kf[ct][0] = *(const bf16x8*)(kp);
      kf[ct][1] = *(const bf16x8*)(kp + 32);
      const unsigned short* vp = Vb + (long)(ct * 16 + ln) * M_ROWS + kv0 + quad * 8;
      vf[ct][0] = *(const bf16x8*)(vp);
      vf[ct][1] = *(const bf16x8*)(vp + 32);
    }
  };

  auto iter = [&](bf16x8 (&kf)[4][2], bf16x8 (&vf)[4][2], int kt) {
    const int kv0 = kt * 64;
    const bool aAct = (kt < nkt1);

    floatx4 sB[4], sA[4];
#pragma unroll
    for (int ct = 0; ct < 4; ct++) {
      sB[ct] = (floatx4){0.f, 0.f, 0.f, 0.f};
      sB[ct] = __builtin_amdgcn_mfma_f32_16x16x32_bf16(kf[ct][0], qfB[0], sB[ct], 0, 0, 0);
      sB[ct] = __builtin_amdgcn_mfma_f32_16x16x32_bf16(kf[ct][1], qfB[1], sB[ct], 0, 0, 0);
    }
    if (aAct) {
#pragma unroll
      for (int ct = 0; ct < 4; ct++) {
        sA[ct] = (floatx4){0.f, 0.f, 0.f, 0.f};
        sA[ct] = __builtin_amdgcn_mfma_f32_16x16x32_bf16(kf[ct][0], qfA[0], sA[ct], 0, 0, 0);
        sA[ct] = __builtin_amdgcn_mfma_f32_16x16x32_bf16(kf[ct][1], qfA[1], sA[ct], 0, 0, 0);
      }
    }

    // softmax B
    {
      float tmax = -1e30f;
      if (kt == nkt2 - 1) {
        const int qg = q0B + ln;
#pragma unroll
        for (int ct = 0; ct < 4; ct++) {
          const int kvb = kv0 + ct * 16 + quad * 4;
#pragma unroll
          for (int reg = 0; reg < 4; reg++) {
            float sv = sB[ct][reg];
            if (kvb + reg > qg) sv = -1e30f;
            sB[ct][reg] = sv;
            tmax = fmaxf(tmax, sv);
          }
        }
      } else {
#pragma unroll
        for (int ct = 0; ct < 4; ct++)
#pragma unroll
          for (int reg = 0; reg < 4; reg++) tmax = fmaxf(tmax, sB[ct][reg]);
      }
      tmax = fmaxf(tmax, __shfl_xor(tmax, 16, 64));
      tmax = fmaxf(tmax, __shfl_xor(tmax, 32, 64));
      const float mnew = fmaxf(mB, tmax);
      const float alpha = exp2f(mB - mnew);
      mB = mnew;
      float rsum = 0.f;
#pragma unroll
      for (int ct = 0; ct < 4; ct++) {
        u16x4 pk;
#pragma unroll
        for (int reg = 0; reg < 4; reg++) {
          const float p = exp2f(sB[ct][reg] - mB);
          rsum += p;
          pk[reg] = f32_to_bf16(p);
        }
        *(u16x4*)(PbB + ln * PSTR + ct * 16 + quad * 4) = pk;
      }
      rsum += __shfl_xor(rsum, 16, 64);
      rsum += __shfl_xor(rsum, 32, 64);
      lB = lB * alpha + rsum;
#pragma unroll
      for (int nt = 0; nt < 4; nt++)
#pragma unroll
        for (int reg = 0; reg < 4; reg++) oB[nt][reg] *= alpha;
    }

    // softmax A
    if (aAct) {
      float tmax = -1e30f;
      if (kt == nkt1 - 1) {
        const int qg = q0A + ln;
#pragma unroll
        for (int ct = 0; ct < 4; ct++) {
          const int kvb = kv0 + ct * 16 + quad * 4;
#pragma unroll
          for (int reg = 0; reg < 4; reg++) {
            float sv = sA[ct][reg];
            if (kvb + reg > qg) sv = -1e30f;
            sA[ct][reg] = sv;
            tmax = fmaxf(tmax, sv);
          }
        }
      } else {
#pragma unroll
        for (int ct = 0; ct < 4; ct++)
#pragma unroll
          for (int reg = 0; reg < 4; reg++) tmax = fmaxf(tmax, sA[ct][reg]);
      }
      tmax = fmaxf(tmax, __shfl_xor(tmax, 16, 64));
      tmax = fmaxf(tmax, __shfl_xor(tmax, 32, 64));
      const float mnew = fmaxf(mA, tmax);
      const float alpha = exp2f(mA - mnew);
      mA = mnew;
      float rsum = 0.f;
#pragma unroll
      for (int ct = 0; ct < 4; ct++) {
        u16x4 pk;
#pragma unroll
        for (int reg = 0; reg < 4; reg++) {
          const float p = exp2f(sA[ct][reg] - mA);
          rsum += p;
          pk[reg] = f32_to_bf16(p);
        }
        *(u16x4*)(PbA + ln * PSTR + ct * 16 + quad * 4) = pk;
      }
      rsum += __shfl_xor(rsum, 16, 64);
      rsum += __shfl_xor(rsum, 32, 64);
      lA = lA * alpha + rsum;
#pragma unroll
      for (int nt = 0; nt < 4; nt++)
#pragma unroll
        for (int reg = 0; reg < 4; reg++) oA[nt][reg] *= alpha;
    }

    __builtin_amdgcn_wave_barrier();

    {
      bf16x8 p0 = *(const bf16x8*)(PbB + ln * PSTR + quad * 8);
      bf16x8 p1 = *(const bf16x8*)(PbB + ln * PSTR + 32 + quad * 8);
#pragma unroll
      for (int nt = 0; nt < 4; nt++) {
        oB[nt] = __builtin_amdgcn_mfma_f32_16x16x32_bf16(vf[nt][0], p0, oB[nt], 0, 0, 0);
        oB[nt] = __builtin_amdgcn_mfma_f32_16x16x32_bf16(vf[nt][1], p1, oB[nt], 0, 0, 0);
      }
    }
    if (aAct) {
      bf16x8 p0 = *(const bf16x8*)(PbA + ln * PSTR + quad * 8);
      bf16x8 p1 = *(const bf16x8*)(PbA + ln * PSTR + 32 + quad * 8);
#pragma unroll
      for (int nt = 0; nt < 4; nt++) {
        oA[nt] = __builtin_amdgcn_mfma_f32_16x16x32_bf16(vf[nt][0], p0, oA[nt], 0, 0, 0);
        oA[nt] = __builtin_amdgcn_mfma_f32_16x16x32_bf16(vf[nt][1], p1, oA[nt], 0, 0, 0);
      }
    }
    __builtin_amdgcn_wave_barrier();
  };

  // software-pipelined main loop: buffers ping-pong, loads lead by one iter
  bf16x8 kf0[4][2], vf0[4][2], kf1[4][2], vf1[4][2];
  loadKV(kf0, vf0, 0);
#pragma unroll 1
  for (int kt = 0; kt < nkt2; kt += 2) {
    if (kt + 1 < nkt2) loadKV(kf1, vf1, kt + 1);
    iter(kf0, vf0, kt);
    if (kt + 1 >= nkt2) break;
    if (kt + 2 < nkt2) loadKV(kf0, vf0, kt + 2);
    iter(kf1, vf1, kt + 1);
  }

  // epilogues
  {
    const float inv = 1.0f / lA;
    unsigned short* op = O + (long)b * S_LEN * D_MODEL + (long)(q0A + ln) * D_MODEL + h * D_HEAD;
#pragma unroll
    for (int nt = 0; nt < 4; nt++) {
      u16x4 pk;
#pragma unroll
      for (int reg = 0; reg < 4; reg++) pk[reg] = f32_to_bf16(oA[nt][reg] * inv);
      *(u16x4*)(op + nt * 16 + quad * 4) = pk;
    }
  }
  {
    const float inv = 1.0f / lB;
    unsigned short* op = O + (long)b * S_LEN * D_MODEL + (long)(q0B + ln) * D_MODEL + h * D_HEAD;
#pragma unroll
    for (int nt = 0; nt < 4; nt++) {
      u16x4 pk;
#pragma unroll
      for (int reg = 0; reg < 4; reg++) pk[reg] = f32_to_bf16(oB[nt][reg] * inv);
      *(u16x4*)(op + nt * 16 + quad * 4) = pk;
    }
  }
}

// ---------------------------------------------------------------------------
extern "C" void kernel_launch(void* const* d_in, const int* in_sizes, int n_in,
                              void* d_out, int out_size, void* d_ws, size_t ws_size,
                              hipStream_t stream) {
  const float* q = (const float*)d_in[0];
  const float* k = (const float*)d_in[1];
  const float* v = (const float*)d_in[2];
  // d_in[3] = causal mask (hardcoded)
  const float* w_q = (const float*)d_in[4];
  const float* b_q = (const float*)d_in[5];
  const float* w_k = (const float*)d_in[6];
  const float* b_k = (const float*)d_in[7];
  const float* w_v = (const float*)d_in[8];
  const float* b_v = (const float*)d_in[9];
  const float* w_o = (const float*)d_in[10];
  const float* b_o = (const float*)d_in[11];
  float* out = (float*)d_out;

  unsigned short* ws = (unsigned short*)d_ws;
  const long NE = (long)M_ROWS * D_MODEL;  // 4M elems = 8 MiB bf16
  const bool xpre = (ws_size >= (size_t)7 * NE * sizeof(unsigned short));  // 56 MiB

  unsigned short *Qp, *Kp, *Vpt, *AO, *Wb, *Xb;
  if (xpre) {
    Qp = ws;             // [0, NE)
    Kp = ws + NE;        // [NE, 2NE)
    Vpt = ws + 2 * NE;   // [2NE, 3NE)
    Wb = ws + 3 * NE;    // [3NE, 4NE)   4 x 1M bf16 weights
    Xb = ws + 4 * NE;    // [4NE, 7NE)   3 x NE bf16 inputs
    AO = ws + 4 * NE;    // aliases Xb_q (dead after qkv_gemm)
  } else {
    Qp = ws;
    Kp = ws + NE;
    Vpt = ws + 2 * NE;
    AO = ws + 3 * NE;
    Wb = ws + 4 * NE;
    Xb = nullptr;
  }

  cvt_w<<<dim3(256, 4), 256, 0, stream>>>(w_q, w_k, w_v, w_o, Wb);
  if (xpre) {
    cvt_x<<<dim3(512, 3), 256, 0, stream>>>(q, k, v, Xb);
    qkv_gemm<true><<<dim3(M_ROWS / 128, GN / 128, 3), 256, 0, stream>>>(
        q, k, v, Xb, Wb, b_q, b_k, b_v, Qp, Kp, Vpt);
  } else {
    qkv_gemm<false><<<dim3(M_ROWS / 128, GN / 128, 3), 256, 0, stream>>>(
        q, k, v, nullptr, Wb, b_q, b_k, b_v, Qp, Kp, Vpt);
  }
  attn_causal<<<dim3(2 * N_HEADS, 64), 64, 0, stream>>>(Qp, Kp, Vpt, AO);
  out_gemm<<<dim3(M_ROWS / 64, GN / 128), 256, 0, stream>>>(AO, Wb + 3 * (1 << 20), b_o, out);
}